// Round 4
// baseline (4356.648 us; speedup 1.0000x reference)
//
#include <hip/hip_runtime.h>
#include <hip/hip_bf16.h>

#define NNODES 10000
#define TLEN 24
#define INDIM 16
#define HID 128
#define GDIM 512   // 4*HID (LSTM gates) == HEADS*HID (GAT)
#define NB_LSTM 632  // 2 layers x 79 m-tiles x 4 col-blocks

typedef __hip_bfloat16 bf16;
typedef short v8s __attribute__((ext_vector_type(8)));
typedef float v4f __attribute__((ext_vector_type(4)));

__device__ inline float u2f(unsigned u){ return __uint_as_float(u); }

__device__ inline void unpack8(uint4 v, float* f){
  f[0]=u2f(v.x<<16); f[1]=u2f(v.x&0xFFFF0000u);
  f[2]=u2f(v.y<<16); f[3]=u2f(v.y&0xFFFF0000u);
  f[4]=u2f(v.z<<16); f[5]=u2f(v.z&0xFFFF0000u);
  f[6]=u2f(v.w<<16); f[7]=u2f(v.w&0xFFFF0000u);
}

__device__ inline float sigm(float x){ return 1.f/(1.f+__expf(-x)); }

// ---------------------------------------------------------------------------
// Convert the 11 f32 weight matrices used as MFMA B-operands to bf16.
// Order: wih0,whh0,wih1,whh1, wl0,wr0,pw0, wl1,wr1,pw1 (65536 each), mow0 (16384).
// wl/wr adjacency gives the concatenated [1024,128] GAT transform matrix.
// ---------------------------------------------------------------------------
__global__ __launch_bounds__(256) void conv_w_k(
    const float* s0, const float* s1, const float* s2, const float* s3,
    const float* s4, const float* s5, const float* s6, const float* s7,
    const float* s8, const float* s9, const float* s10, bf16* __restrict__ dst)
{
  int idx = blockIdx.x*256 + threadIdx.x;
  if (idx >= 671744) return;
  int c = idx >> 16;
  float v;
  if (c < 10){
    const float* srcs[10] = {s0,s1,s2,s3,s4,s5,s6,s7,s8,s9};
    v = srcs[c][idx & 0xFFFF];
  } else {
    v = s10[idx - 655360];
  }
  dst[idx] = __float2bfloat16(v);
}

// ---------------------------------------------------------------------------
// Prep: folded MLP-in weights (f32), presummed LSTM biases, concat GAT biases.
// ---------------------------------------------------------------------------
__global__ void prep_w_k(
    const float* __restrict__ miw0, const float* __restrict__ mib0,
    const float* __restrict__ miw1, const float* __restrict__ mib1,
    const float* __restrict__ bih0, const float* __restrict__ bhh0,
    const float* __restrict__ bih1, const float* __restrict__ bhh1,
    const float* __restrict__ bl0, const float* __restrict__ br0,
    const float* __restrict__ bl1, const float* __restrict__ br1,
    float* __restrict__ Wp, float* __restrict__ bp,
    float* __restrict__ bsum, float* __restrict__ gblr)
{
  int t = threadIdx.x;
  for (int idx = t; idx < HID*INDIM; idx += 256){
    int j = idx >> 4, d = idx & 15;
    float s = 0.f;
    for (int k=0;k<HID;k++) s += miw1[j*HID+k] * miw0[k*INDIM+d];
    Wp[idx] = s;
  }
  for (int j = t; j < HID; j += 256){
    float s = mib1[j];
    for (int k=0;k<HID;k++) s += miw1[j*HID+k] * mib0[k];
    bp[j] = s;
  }
  for (int i = t; i < GDIM; i += 256){
    bsum[i]        = bih0[i] + bhh0[i];
    bsum[GDIM + i] = bih1[i] + bhh1[i];
  }
  for (int i = t; i < GDIM; i += 256){
    gblr[i]          = bl0[i];
    gblr[GDIM + i]   = br0[i];
    gblr[1024 + i]   = bl1[i];
    gblr[1536 + i]   = br1[i];
  }
}

// ---------------------------------------------------------------------------
// MLP-in: X0[t*N+n][j] = relu(bp[j] + x[n,t,:].Wp[j,:]). 4 outputs/thread.
// ---------------------------------------------------------------------------
__global__ __launch_bounds__(256) void mlp_in_k(
    const float* __restrict__ x, const float* __restrict__ Wp,
    const float* __restrict__ bp, bf16* __restrict__ X0)
{
  int tid = threadIdx.x;
  int mloc = tid >> 5, jg = tid & 31;
  int m = blockIdx.x*8 + mloc;
  if (m >= TLEN*NNODES) return;
  int t = m / NNODES, n = m - t*NNODES;
  const float* xr = x + ((size_t)n*TLEN + t)*INDIM;
  float4 xv0 = *(const float4*)(xr);
  float4 xv1 = *(const float4*)(xr + 4);
  float4 xv2 = *(const float4*)(xr + 8);
  float4 xv3 = *(const float4*)(xr + 12);
  float4 bv = *(const float4*)(bp + jg*4);
  float bb[4] = {bv.x, bv.y, bv.z, bv.w};
  bf16 o[4];
  #pragma unroll
  for (int jj=0;jj<4;jj++){
    const float* wr = Wp + (jg*4+jj)*INDIM;
    float4 w0 = *(const float4*)(wr);
    float4 w1 = *(const float4*)(wr + 4);
    float4 w2 = *(const float4*)(wr + 8);
    float4 w3 = *(const float4*)(wr + 12);
    float s = bb[jj]
      + xv0.x*w0.x + xv0.y*w0.y + xv0.z*w0.z + xv0.w*w0.w
      + xv1.x*w1.x + xv1.y*w1.y + xv1.z*w1.z + xv1.w*w1.w
      + xv2.x*w2.x + xv2.y*w2.y + xv2.z*w2.z + xv2.w*w2.w
      + xv3.x*w3.x + xv3.y*w3.y + xv3.z*w3.z + xv3.w*w3.w;
    s = s > 0.f ? s : 0.f;
    o[jj] = __float2bfloat16(s);
  }
  *(uint2*)(X0 + (size_t)m*HID + jg*4) = *(const uint2*)o;
}

// ---------------------------------------------------------------------------
// Persistent LSTM: 2 layers x 24 steps, pipelined. Block bid<316 -> layer1,
// else layer2. Block (mb, cb) owns rows [128mb,128mb+128) x hidden cols
// [32cb,32cb+32) of all 4 gates. c-state in registers. Device-scope atomic
// barrier between pipeline iterations (co-residency: LDS 20.5KB -> 8/CU,
// launch_bounds(256,3) -> >=3 blocks/CU = 768 >= 632).
// ---------------------------------------------------------------------------
__global__ __launch_bounds__(256, 3) void lstm_all(
    const bf16* __restrict__ X0, const bf16* __restrict__ Wb,
    const float* __restrict__ bsum,
    bf16* __restrict__ h1a, bf16* __restrict__ h1b,
    bf16* __restrict__ h2a, bf16* __restrict__ h2b,
    const bf16* __restrict__ zb, unsigned* __restrict__ ctr)
{
  __shared__ __align__(16) bf16 As[128*40];
  __shared__ __align__(16) bf16 Bs[128*40];
  const int tid = threadIdx.x;
  const int bid = blockIdx.x;
  const int lay = bid >= 316 ? 1 : 0;
  const int b = lay ? bid - 316 : bid;
  const int mb = b % 79, cb = b / 79;
  const int m0 = mb*128;
  const int lane = tid & 63, wave = tid >> 6;
  const int r16 = lane & 15, quad = lane >> 4;

  const bf16* Wih = Wb + (size_t)lay*131072;
  const bf16* Whh = Wih + 65536;
  bf16* h1buf[2] = {h1a, h1b};
  bf16* h2buf[2] = {h2a, h2b};

  // per-lane biases (8: gate x half), constant across steps
  float bias_r[8];
  #pragma unroll
  for (int g=0; g<4; g++)
    #pragma unroll
    for (int half=0; half<2; half++)
      bias_r[g*2+half] = bsum[lay*GDIM + g*HID + cb*32 + half*16 + r16];

  float creg[16];   // [mi*8 + r*2 + half]
  #pragma unroll
  for (int i=0;i<16;i++) creg[i] = 0.f;

  for (int it=0; it<25; it++){
    const bool active = lay ? (it >= 1) : (it <= 23);
    if (active){
      const int t = lay ? it-1 : it;
      const bf16* Xp; const bf16* Hp; bf16* Ho;
      if (!lay){
        Xp = X0 + (size_t)t*NNODES*HID;
        Hp = (t==0) ? zb : h1buf[(t-1)&1];
        Ho = h1buf[t&1];
      } else {
        Xp = h1buf[t&1];
        Hp = (t==0) ? zb : h2buf[(t-1)&1];
        Ho = h2buf[t&1];
      }

      v4f acc[2][8];
      #pragma unroll
      for (int a=0;a<2;a++)
        #pragma unroll
        for (int bb=0;bb<8;bb++) acc[a][bb] = (v4f)0.f;

      #pragma unroll
      for (int ph=0; ph<2; ph++){
        const bf16* Ap = ph ? Hp : Xp;
        const bf16* Wp = ph ? Whh : Wih;
        for (int k0=0; k0<128; k0+=32){
          #pragma unroll
          for (int i=0;i<2;i++){
            int li = tid + i*256;
            int row = li >> 2, q4 = li & 3;
            uint4 va = make_uint4(0,0,0,0);
            int gm = m0 + row;
            if (gm < NNODES) va = *(const uint4*)(Ap + (size_t)gm*HID + k0 + q4*8);
            *(uint4*)(As + row*40 + q4*8) = va;
            int wr = ((row>>5)*HID) + cb*32 + (row & 31);
            uint4 vb = *(const uint4*)(Wp + (size_t)wr*HID + k0 + q4*8);
            *(uint4*)(Bs + row*40 + q4*8) = vb;
          }
          __syncthreads();
          v8s av[2], bv[8];
          #pragma unroll
          for (int mi=0;mi<2;mi++)
            av[mi] = *(const v8s*)(As + (wave*32 + mi*16 + r16)*40 + quad*8);
          #pragma unroll
          for (int ni=0;ni<8;ni++)
            bv[ni] = *(const v8s*)(Bs + (ni*16 + r16)*40 + quad*8);
          #pragma unroll
          for (int mi=0;mi<2;mi++)
            #pragma unroll
            for (int ni=0;ni<8;ni++)
              acc[mi][ni] = __builtin_amdgcn_mfma_f32_16x16x32_bf16(av[mi], bv[ni], acc[mi][ni], 0, 0, 0);
          __syncthreads();
        }
      }

      #pragma unroll
      for (int mi=0;mi<2;mi++){
        #pragma unroll
        for (int r=0;r<4;r++){
          int row = m0 + wave*32 + mi*16 + quad*4 + r;
          if (row >= NNODES) continue;
          #pragma unroll
          for (int half=0; half<2; half++){
            int hcol = cb*32 + half*16 + r16;
            float iv = acc[mi][0+half][r] + bias_r[0+half];
            float fv = acc[mi][2+half][r] + bias_r[2+half];
            float gv = acc[mi][4+half][r] + bias_r[4+half];
            float ov = acc[mi][6+half][r] + bias_r[6+half];
            float ig = sigm(iv), fg = sigm(fv);
            float gg = tanhf(gv), og = sigm(ov);
            int ci = mi*8 + r*2 + half;
            float cn = fg*creg[ci] + ig*gg;
            creg[ci] = cn;
            Ho[(size_t)row*HID + hcol] = __float2bfloat16(og*tanhf(cn));
          }
        }
      }
    }

    // grid barrier (device scope)
    __syncthreads();
    if (tid == 0){
      __hip_atomic_fetch_add(ctr, 1u, __ATOMIC_RELEASE, __HIP_MEMORY_SCOPE_AGENT);
      unsigned target = (unsigned)NB_LSTM * (unsigned)(it+1);
      while (__hip_atomic_load(ctr, __ATOMIC_ACQUIRE, __HIP_MEMORY_SCOPE_AGENT) < target)
        __builtin_amdgcn_s_sleep(2);
    }
    __syncthreads();
  }
}

// ---------------------------------------------------------------------------
// Generic bf16 GEMM: C[M,N] = act(A[M,K] @ B[N,K]^T + bias_f32[N]), bf16 out.
// ---------------------------------------------------------------------------
template<int ACT>
__global__ __launch_bounds__(256) void gemm_bt(
    const bf16* __restrict__ A, const bf16* __restrict__ B,
    const float* __restrict__ bias, bf16* __restrict__ C,
    int M, int N, int K)
{
  __shared__ __align__(16) bf16 As[128*40];
  __shared__ __align__(16) bf16 Bs[128*40];
  const int tid = threadIdx.x;
  const int m0 = blockIdx.x*128, n0 = blockIdx.y*128;
  const int lane = tid & 63, wave = tid >> 6;
  const int r16 = lane & 15, quad = lane >> 4;

  v4f acc[2][8];
  #pragma unroll
  for (int a=0;a<2;a++)
    #pragma unroll
    for (int b=0;b<8;b++) acc[a][b] = (v4f)0.f;

  for (int k0=0; k0<K; k0+=32){
    #pragma unroll
    for (int i=0;i<2;i++){
      int li = tid + i*256;
      int row = li >> 2, q4 = li & 3;
      uint4 va = make_uint4(0,0,0,0);
      int gm = m0 + row;
      if (gm < M) va = *(const uint4*)(A + (size_t)gm*K + k0 + q4*8);
      *(uint4*)(As + row*40 + q4*8) = va;
      uint4 vb = make_uint4(0,0,0,0);
      int gn = n0 + row;
      if (gn < N) vb = *(const uint4*)(B + (size_t)gn*K + k0 + q4*8);
      *(uint4*)(Bs + row*40 + q4*8) = vb;
    }
    __syncthreads();
    v8s av[2], bv[8];
    #pragma unroll
    for (int mi=0;mi<2;mi++)
      av[mi] = *(const v8s*)(As + (wave*32 + mi*16 + r16)*40 + quad*8);
    #pragma unroll
    for (int ni=0;ni<8;ni++)
      bv[ni] = *(const v8s*)(Bs + (ni*16 + r16)*40 + quad*8);
    #pragma unroll
    for (int mi=0;mi<2;mi++)
      #pragma unroll
      for (int ni=0;ni<8;ni++)
        acc[mi][ni] = __builtin_amdgcn_mfma_f32_16x16x32_bf16(av[mi], bv[ni], acc[mi][ni], 0, 0, 0);
    __syncthreads();
  }

  #pragma unroll
  for (int mi=0;mi<2;mi++){
    #pragma unroll
    for (int r=0;r<4;r++){
      int row = m0 + wave*32 + mi*16 + quad*4 + r;
      if (row >= M) continue;
      #pragma unroll
      for (int ni=0;ni<8;ni++){
        int col = n0 + ni*16 + r16;
        float v = acc[mi][ni][r] + bias[col];
        if (ACT == 1) v = v > 0.f ? v : 0.f;
        C[(size_t)row*N + col] = __float2bfloat16(v);
      }
    }
  }
}

// ---------------------------------------------------------------------------
// CSR build
// ---------------------------------------------------------------------------
__global__ void deg_count_k(const int* __restrict__ dst, int* __restrict__ deg, int E){
  int e = blockIdx.x*256 + threadIdx.x;
  if (e < E){
    unsigned d = (unsigned)dst[e];
    if (d < (unsigned)NNODES) atomicAdd(&deg[d], 1);
  }
}

__global__ void scan_k(const int* __restrict__ deg, int* __restrict__ offs,
                       int* __restrict__ cursor, int n)
{
  __shared__ int part[256];
  __shared__ int base[256];
  int t = threadIdx.x;
  int lo = t*40, hi = lo+40;
  if (lo > n) lo = n;
  if (hi > n) hi = n;
  int s = 0;
  for (int i=lo;i<hi;i++) s += deg[i];
  part[t] = s;
  __syncthreads();
  if (t == 0){
    int run=0;
    for (int i=0;i<256;i++){ base[i]=run; run+=part[i]; }
    offs[n] = run;
  }
  __syncthreads();
  int run = base[t];
  for (int i=lo;i<hi;i++){ offs[i]=run; cursor[i]=run; run += deg[i]; }
}

__global__ void fill_k(const int* __restrict__ dst, int* __restrict__ cursor,
                       int* __restrict__ eids, int E){
  int e = blockIdx.x*256 + threadIdx.x;
  if (e < E){
    unsigned d = (unsigned)dst[e];
    if (d < (unsigned)NNODES){
      int p = atomicAdd(&cursor[d], 1);
      eids[p] = e;
    }
  }
}

// ---------------------------------------------------------------------------
// GATv2 edge scores from combined xc=[xl|xr] rows of stride 1024.
// ---------------------------------------------------------------------------
__global__ __launch_bounds__(256) void gat_score(
    const int* __restrict__ src, const int* __restrict__ dst,
    const bf16* __restrict__ xc, const float* __restrict__ att,
    float* __restrict__ score, int E)
{
  int e = blockIdx.x*4 + (threadIdx.x >> 6);
  if (e >= E) return;
  int lane = threadIdx.x & 63;
  unsigned s = (unsigned)src[e], d = (unsigned)dst[e];
  if (s >= NNODES) s = 0;
  if (d >= NNODES) d = 0;
  float fl[8], fr[8];
  unpack8(*(const uint4*)(xc + (size_t)s*1024 + lane*8), fl);
  unpack8(*(const uint4*)(xc + (size_t)d*1024 + 512 + lane*8), fr);
  float4 a0 = *(const float4*)(att + lane*8);
  float4 a1 = *(const float4*)(att + lane*8 + 4);
  float fa[8] = {a0.x,a0.y,a0.z,a0.w,a1.x,a1.y,a1.z,a1.w};
  float p = 0.f;
  #pragma unroll
  for (int q=0;q<8;q++){
    float v = fl[q] + fr[q];
    v = v > 0.f ? v : 0.2f*v;
    p += v*fa[q];
  }
  p += __shfl_xor(p, 1); p += __shfl_xor(p, 2);
  p += __shfl_xor(p, 4); p += __shfl_xor(p, 8);
  if ((lane & 15) == 0)
    score[(size_t)e*4 + (lane>>4)] = p;
}

// ---------------------------------------------------------------------------
// Segment softmax + aggregation (atomic-free, 1 wave/node, CSR 2-sweep).
// ---------------------------------------------------------------------------
__global__ __launch_bounds__(256) void gat_agg(
    const int* __restrict__ offs, const int* __restrict__ eids, const int* __restrict__ src,
    const float* __restrict__ score, const bf16* __restrict__ xc,
    const float* __restrict__ gbias, bf16* __restrict__ agg)
{
  int d = blockIdx.x*4 + (threadIdx.x >> 6);
  if (d >= NNODES) return;
  int lane = threadIdx.x & 63;
  int head = lane >> 4;
  int i0 = offs[d], i1 = offs[d+1];
  float mx = -3.4e38f;
  for (int i=i0; i<i1; i++){
    int e = eids[i];
    mx = fmaxf(mx, score[(size_t)e*4 + head]);
  }
  float den = 0.f;
  float acc[8] = {0,0,0,0,0,0,0,0};
  for (int i=i0; i<i1; i++){
    int e = eids[i];
    unsigned s = (unsigned)src[e];
    if (s >= NNODES) s = 0;
    float w = __expf(score[(size_t)e*4 + head] - mx);
    den += w;
    float fx[8];
    unpack8(*(const uint4*)(xc + (size_t)s*1024 + lane*8), fx);
    #pragma unroll
    for (int q=0;q<8;q++) acc[q] += w*fx[q];
  }
  float r = 1.f/(den + 1e-16f);
  float4 b0 = *(const float4*)(gbias + lane*8);
  float4 b1 = *(const float4*)(gbias + lane*8 + 4);
  float fb[8] = {b0.x,b0.y,b0.z,b0.w,b1.x,b1.y,b1.z,b1.w};
  #pragma unroll
  for (int q=0;q<8;q++)
    agg[(size_t)d*GDIM + lane*8 + q] = __float2bfloat16(acc[q]*r + fb[q]);
}

// ---------------------------------------------------------------------------
// Final linear (N=24): f32 weights, f32 out.
// ---------------------------------------------------------------------------
__global__ __launch_bounds__(256) void mlp_final_k(
    const bf16* __restrict__ a, const float* __restrict__ w,
    const float* __restrict__ b, float* __restrict__ out)
{
  int g = blockIdx.x*256 + threadIdx.x;
  if (g >= NNODES*24) return;
  int j = g % 24;
  int row = g / 24;
  const bf16* ar = a + (size_t)row*HID;
  const float* wr = w + (size_t)j*HID;
  float s = b[j];
  for (int k=0;k<HID;k+=8){
    float fa[8];
    unpack8(*(const uint4*)(ar+k), fa);
    float4 w0 = *(const float4*)(wr + k);
    float4 w1 = *(const float4*)(wr + k + 4);
    s += fa[0]*w0.x + fa[1]*w0.y + fa[2]*w0.z + fa[3]*w0.w
       + fa[4]*w1.x + fa[5]*w1.y + fa[6]*w1.z + fa[7]*w1.w;
  }
  out[g] = s;
}

// ---------------------------------------------------------------------------

extern "C" void kernel_launch(void* const* d_in, const int* in_sizes, int n_in,
                              void* d_out, int out_size, void* d_ws, size_t ws_size,
                              hipStream_t stream)
{
  const float* x   = (const float*)d_in[0];
  const int*   ei  = (const int*)d_in[1];
  const int E = in_sizes[1] / 2;
  const int* srcp = ei;
  const int* dstp = ei + E;

  const float* miw0 = (const float*)d_in[2];
  const float* mib0 = (const float*)d_in[3];
  const float* miw1 = (const float*)d_in[4];
  const float* mib1 = (const float*)d_in[5];
  const float* wih0 = (const float*)d_in[6];
  const float* whh0 = (const float*)d_in[7];
  const float* bih0 = (const float*)d_in[8];
  const float* bhh0 = (const float*)d_in[9];
  const float* wih1 = (const float*)d_in[10];
  const float* whh1 = (const float*)d_in[11];
  const float* bih1 = (const float*)d_in[12];
  const float* bhh1 = (const float*)d_in[13];
  const float* g_wl[2]   = {(const float*)d_in[14], (const float*)d_in[22]};
  const float* g_bl[2]   = {(const float*)d_in[15], (const float*)d_in[23]};
  const float* g_wr[2]   = {(const float*)d_in[16], (const float*)d_in[24]};
  const float* g_br[2]   = {(const float*)d_in[17], (const float*)d_in[25]};
  const float* g_att[2]  = {(const float*)d_in[18], (const float*)d_in[26]};
  const float* g_bias[2] = {(const float*)d_in[19], (const float*)d_in[27]};
  const float* g_pw[2]   = {(const float*)d_in[20], (const float*)d_in[28]};
  const float* g_pb[2]   = {(const float*)d_in[21], (const float*)d_in[29]};
  const float* mow0 = (const float*)d_in[30];
  const float* mob0 = (const float*)d_in[31];
  const float* mow1 = (const float*)d_in[32];
  const float* mob1 = (const float*)d_in[33];
  (void)n_in; (void)out_size; (void)ws_size;

  // ---- workspace layout ----
  char* base = (char*)d_ws;
  size_t off = 0;
  auto carve = [&](size_t n)->char*{
    char* p = base + off;
    off = (off + n + 255) & ~(size_t)255;
    return p;
  };
  char*  X0r = carve((size_t)TLEN*NNODES*HID*2);   // 61,440,000
  bf16*  h1a = (bf16*)carve((size_t)NNODES*HID*2);
  bf16*  h1b = (bf16*)carve((size_t)NNODES*HID*2);
  bf16*  h2a = (bf16*)carve((size_t)NNODES*HID*2);
  bf16*  h2b = (bf16*)carve((size_t)NNODES*HID*2);
  bf16*  zb  = (bf16*)carve((size_t)NNODES*HID*2);
  float* Wp  = (float*)carve(HID*INDIM*4);
  float* bp  = (float*)carve(HID*4);
  float* bsum= (float*)carve(2*GDIM*4);
  float* gblr= (float*)carve(2*1024*4);
  unsigned* ctr = (unsigned*)carve(256);
  bf16*  wbf = (bf16*)carve((size_t)671744*2);
  float* score = (float*)carve((size_t)E*4*4);
  int*   offsb = (int*)carve((size_t)(NNODES+1)*4);
  int*   curs  = (int*)carve((size_t)NNODES*4);
  int*   eids  = (int*)carve((size_t)E*4);
  int*   deg   = (int*)carve((size_t)NNODES*4);
  bf16*  agg   = (bf16*)carve((size_t)NNODES*GDIM*2);

  // wbf sub-pointers (conv_w_k chunk order)
  const bf16* wlr0b = wbf + 262144;   // wl0|wr0 contiguous [1024,128]
  const bf16* pw0b  = wbf + 393216;
  const bf16* wlr1b = wbf + 458752;   // wl1|wr1 contiguous
  const bf16* pw1b  = wbf + 524288 + 65536;
  const bf16* mow0b = wbf + 655360;
  const bf16* wlrb[2] = {wlr0b, wlr1b};
  const bf16* pwb[2]  = {pw0b, pw1b};

  // X0 region aliases (dead after LSTM)
  bf16* X0 = (bf16*)X0r;
  bf16* xc = (bf16*)X0r;                      // [10000,1024] = xl|xr
  bf16* z2 = (bf16*)(X0r + 20480000);
  bf16* z3 = (bf16*)(X0r + 23040000);
  bf16* o0 = (bf16*)(X0r + 25600000);

  // ---- prep ----
  conv_w_k<<<2624, 256, 0, stream>>>(wih0, whh0, wih1, whh1,
                                     g_wl[0], g_wr[0], g_pw[0],
                                     g_wl[1], g_wr[1], g_pw[1], mow0, wbf);
  prep_w_k<<<1, 256, 0, stream>>>(miw0, mib0, miw1, mib1,
                                  bih0, bhh0, bih1, bhh1,
                                  g_bl[0], g_br[0], g_bl[1], g_br[1],
                                  Wp, bp, bsum, gblr);
  hipMemsetAsync(zb, 0, (size_t)NNODES*HID*2, stream);
  hipMemsetAsync(ctr, 0, 256, stream);
  hipMemsetAsync(deg, 0, (size_t)NNODES*4, stream);

  // ---- MLP in ----
  mlp_in_k<<<(TLEN*NNODES)/8, 256, 0, stream>>>(x, Wp, bp, X0);

  // ---- CSR build ----
  deg_count_k<<<(E+255)/256, 256, 0, stream>>>(dstp, deg, E);
  scan_k<<<1, 256, 0, stream>>>(deg, offsb, curs, NNODES);
  fill_k<<<(E+255)/256, 256, 0, stream>>>(dstp, curs, eids, E);

  // ---- LSTM (one persistent kernel, both layers, 24 steps) ----
  lstm_all<<<NB_LSTM, 256, 0, stream>>>(X0, wbf, bsum, h1a, h1b, h2a, h2b, zb, ctr);
  const bf16* z = h2b;   // t=23 -> buf[1]

  // ---- GAT layers ----
  const bf16* zin = z;
  bf16* zouts[2] = {z2, z3};
  for (int l=0; l<2; l++){
    gemm_bt<0><<<dim3(79,8), 256, 0, stream>>>(zin, wlrb[l], gblr + l*1024, xc, NNODES, 1024, HID);
    gat_score<<<(E+3)/4, 256, 0, stream>>>(srcp, dstp, xc, g_att[l], score, E);
    gat_agg<<<(NNODES+3)/4, 256, 0, stream>>>(offsb, eids, srcp, score, xc, g_bias[l], agg);
    gemm_bt<1><<<dim3(79,1), 256, 0, stream>>>(agg, pwb[l], g_pb[l], zouts[l], NNODES, HID, GDIM);
    zin = zouts[l];
  }

  // ---- MLP out ----
  gemm_bt<1><<<dim3(79,1), 256, 0, stream>>>(z3, mow0b, mob0, o0, NNODES, HID, HID);
  mlp_final_k<<<(NNODES*24+255)/256, 256, 0, stream>>>(o0, mow1, mob1, (float*)d_out);
}

// Round 5
// 1965.744 us; speedup vs baseline: 2.2163x; 2.2163x over previous
//
#include <hip/hip_runtime.h>
#include <hip/hip_bf16.h>

#define NNODES 10000
#define TLEN 24
#define INDIM 16
#define HID 128
#define GDIM 512   // 4*HID (LSTM gates) == HEADS*HID (GAT)

typedef __hip_bfloat16 bf16;
typedef short v8s __attribute__((ext_vector_type(8)));
typedef float v4f __attribute__((ext_vector_type(4)));

__device__ inline float u2f(unsigned u){ return __uint_as_float(u); }

__device__ inline void unpack8(uint4 v, float* f){
  f[0]=u2f(v.x<<16); f[1]=u2f(v.x&0xFFFF0000u);
  f[2]=u2f(v.y<<16); f[3]=u2f(v.y&0xFFFF0000u);
  f[4]=u2f(v.z<<16); f[5]=u2f(v.z&0xFFFF0000u);
  f[6]=u2f(v.w<<16); f[7]=u2f(v.w&0xFFFF0000u);
}

__device__ inline float sigm(float x){ return 1.f/(1.f+__expf(-x)); }

// ---------------------------------------------------------------------------
// Convert the 11 f32 weight matrices used as MFMA B-operands to bf16.
// Order: wih0,whh0,wih1,whh1, wl0,wr0,pw0, wl1,wr1,pw1 (65536 each), mow0 (16384).
// ---------------------------------------------------------------------------
__global__ __launch_bounds__(256) void conv_w_k(
    const float* s0, const float* s1, const float* s2, const float* s3,
    const float* s4, const float* s5, const float* s6, const float* s7,
    const float* s8, const float* s9, const float* s10, bf16* __restrict__ dst)
{
  int idx = blockIdx.x*256 + threadIdx.x;
  if (idx >= 671744) return;
  int c = idx >> 16;
  float v;
  if (c < 10){
    const float* srcs[10] = {s0,s1,s2,s3,s4,s5,s6,s7,s8,s9};
    v = srcs[c][idx & 0xFFFF];
  } else {
    v = s10[idx - 655360];
  }
  dst[idx] = __float2bfloat16(v);
}

// ---------------------------------------------------------------------------
// Prep: folded MLP-in weights (f32), presummed LSTM biases, concat GAT biases.
// ---------------------------------------------------------------------------
__global__ void prep_w_k(
    const float* __restrict__ miw0, const float* __restrict__ mib0,
    const float* __restrict__ miw1, const float* __restrict__ mib1,
    const float* __restrict__ bih0, const float* __restrict__ bhh0,
    const float* __restrict__ bih1, const float* __restrict__ bhh1,
    const float* __restrict__ bl0, const float* __restrict__ br0,
    const float* __restrict__ bl1, const float* __restrict__ br1,
    float* __restrict__ Wp, float* __restrict__ bp,
    float* __restrict__ bsum, float* __restrict__ gblr)
{
  int t = threadIdx.x;
  for (int idx = t; idx < HID*INDIM; idx += 256){
    int j = idx >> 4, d = idx & 15;
    float s = 0.f;
    for (int k=0;k<HID;k++) s += miw1[j*HID+k] * miw0[k*INDIM+d];
    Wp[idx] = s;
  }
  for (int j = t; j < HID; j += 256){
    float s = mib1[j];
    for (int k=0;k<HID;k++) s += miw1[j*HID+k] * mib0[k];
    bp[j] = s;
  }
  for (int i = t; i < GDIM; i += 256){
    bsum[i]        = bih0[i] + bhh0[i];
    bsum[GDIM + i] = bih1[i] + bhh1[i];
  }
  for (int i = t; i < GDIM; i += 256){
    gblr[i]          = bl0[i];
    gblr[GDIM + i]   = br0[i];
    gblr[1024 + i]   = bl1[i];
    gblr[1536 + i]   = br1[i];
  }
}

// ---------------------------------------------------------------------------
// MLP-in: X0[t*N+n][j] = relu(bp[j] + x[n,t,:].Wp[j,:]). 4 outputs/thread.
// ---------------------------------------------------------------------------
__global__ __launch_bounds__(256) void mlp_in_k(
    const float* __restrict__ x, const float* __restrict__ Wp,
    const float* __restrict__ bp, bf16* __restrict__ X0)
{
  int tid = threadIdx.x;
  int mloc = tid >> 5, jg = tid & 31;
  int m = blockIdx.x*8 + mloc;
  if (m >= TLEN*NNODES) return;
  int t = m / NNODES, n = m - t*NNODES;
  const float* xr = x + ((size_t)n*TLEN + t)*INDIM;
  float4 xv0 = *(const float4*)(xr);
  float4 xv1 = *(const float4*)(xr + 4);
  float4 xv2 = *(const float4*)(xr + 8);
  float4 xv3 = *(const float4*)(xr + 12);
  float4 bv = *(const float4*)(bp + jg*4);
  float bb[4] = {bv.x, bv.y, bv.z, bv.w};
  bf16 o[4];
  #pragma unroll
  for (int jj=0;jj<4;jj++){
    const float* wr = Wp + (jg*4+jj)*INDIM;
    float4 w0 = *(const float4*)(wr);
    float4 w1 = *(const float4*)(wr + 4);
    float4 w2 = *(const float4*)(wr + 8);
    float4 w3 = *(const float4*)(wr + 12);
    float s = bb[jj]
      + xv0.x*w0.x + xv0.y*w0.y + xv0.z*w0.z + xv0.w*w0.w
      + xv1.x*w1.x + xv1.y*w1.y + xv1.z*w1.z + xv1.w*w1.w
      + xv2.x*w2.x + xv2.y*w2.y + xv2.z*w2.z + xv2.w*w2.w
      + xv3.x*w3.x + xv3.y*w3.y + xv3.z*w3.z + xv3.w*w3.w;
    s = s > 0.f ? s : 0.f;
    o[jj] = __float2bfloat16(s);
  }
  *(uint2*)(X0 + (size_t)m*HID + jg*4) = *(const uint2*)o;
}

// ---------------------------------------------------------------------------
// LSTM step, no-LDS variant. Grid 313 blocks x 256 thr. Block owns rows
// [32b,32b+32) x ALL 512 gate cols; wave w owns hidden cols [32w,32w+32) of
// all 4 gates. A/B fragments loaded directly from global (weights L2-hot,
// A rows L1-cached across waves). No __syncthreads, no LDS, no conflicts.
// ---------------------------------------------------------------------------
__global__ __launch_bounds__(256) void lstm_step2(
    const bf16* __restrict__ X, const bf16* __restrict__ Hprev,
    const bf16* __restrict__ Wih, const bf16* __restrict__ Whh,
    const float* __restrict__ bsum,
    float* __restrict__ cst, bf16* __restrict__ Hout)
{
  const int tid = threadIdx.x;
  const int lane = tid & 63, wave = tid >> 6;
  const int r16 = lane & 15, quad = lane >> 4;
  const int m0 = blockIdx.x*32;

  float bias_r[8];
  #pragma unroll
  for (int g=0; g<4; g++)
    #pragma unroll
    for (int half=0; half<2; half++)
      bias_r[g*2+half] = bsum[g*HID + wave*32 + half*16 + r16];

  v4f acc[2][8];
  #pragma unroll
  for (int a=0;a<2;a++)
    #pragma unroll
    for (int b=0;b<8;b++) acc[a][b] = (v4f)0.f;

  // A-row indices (clamped; OOB rows guarded at write)
  int arow[2];
  #pragma unroll
  for (int mi=0;mi<2;mi++){
    int row = m0 + mi*16 + r16;
    arow[mi] = row < NNODES ? row : NNODES-1;
  }

  #pragma unroll
  for (int ph=0; ph<2; ph++){
    const bf16* Ap = ph ? Hprev : X;
    const bf16* Wp = ph ? Whh : Wih;
    #pragma unroll
    for (int k0=0; k0<128; k0+=32){
      v8s av[2], bv[8];
      #pragma unroll
      for (int mi=0;mi<2;mi++)
        av[mi] = *(const v8s*)(Ap + (size_t)arow[mi]*HID + k0 + quad*8);
      #pragma unroll
      for (int g=0; g<4; g++)
        #pragma unroll
        for (int half=0; half<2; half++){
          int wr = g*HID + wave*32 + half*16 + r16;
          bv[g*2+half] = *(const v8s*)(Wp + (size_t)wr*HID + k0 + quad*8);
        }
      #pragma unroll
      for (int mi=0;mi<2;mi++)
        #pragma unroll
        for (int ni=0;ni<8;ni++)
          acc[mi][ni] = __builtin_amdgcn_mfma_f32_16x16x32_bf16(av[mi], bv[ni], acc[mi][ni], 0, 0, 0);
    }
  }

  #pragma unroll
  for (int mi=0;mi<2;mi++){
    #pragma unroll
    for (int r=0;r<4;r++){
      int row = m0 + mi*16 + quad*4 + r;
      if (row >= NNODES) continue;
      #pragma unroll
      for (int half=0; half<2; half++){
        int hcol = wave*32 + half*16 + r16;
        float iv = acc[mi][0+half][r] + bias_r[0+half];
        float fv = acc[mi][2+half][r] + bias_r[2+half];
        float gv = acc[mi][4+half][r] + bias_r[4+half];
        float ov = acc[mi][6+half][r] + bias_r[6+half];
        float ig = sigm(iv), fg = sigm(fv);
        float gg = tanhf(gv), og = sigm(ov);
        size_t ci = (size_t)row*HID + hcol;
        float cn = fg*cst[ci] + ig*gg;
        cst[ci] = cn;
        Hout[ci] = __float2bfloat16(og*tanhf(cn));
      }
    }
  }
}

// ---------------------------------------------------------------------------
// Generic bf16 GEMM: C[M,N] = act(A[M,K] @ B[N,K]^T + bias_f32[N]), bf16 out.
// ---------------------------------------------------------------------------
template<int ACT>
__global__ __launch_bounds__(256) void gemm_bt(
    const bf16* __restrict__ A, const bf16* __restrict__ B,
    const float* __restrict__ bias, bf16* __restrict__ C,
    int M, int N, int K)
{
  __shared__ __align__(16) bf16 As[128*40];
  __shared__ __align__(16) bf16 Bs[128*40];
  const int tid = threadIdx.x;
  const int m0 = blockIdx.x*128, n0 = blockIdx.y*128;
  const int lane = tid & 63, wave = tid >> 6;
  const int r16 = lane & 15, quad = lane >> 4;

  v4f acc[2][8];
  #pragma unroll
  for (int a=0;a<2;a++)
    #pragma unroll
    for (int b=0;b<8;b++) acc[a][b] = (v4f)0.f;

  for (int k0=0; k0<K; k0+=32){
    #pragma unroll
    for (int i=0;i<2;i++){
      int li = tid + i*256;
      int row = li >> 2, q4 = li & 3;
      uint4 va = make_uint4(0,0,0,0);
      int gm = m0 + row;
      if (gm < M) va = *(const uint4*)(A + (size_t)gm*K + k0 + q4*8);
      *(uint4*)(As + row*40 + q4*8) = va;
      uint4 vb = make_uint4(0,0,0,0);
      int gn = n0 + row;
      if (gn < N) vb = *(const uint4*)(B + (size_t)gn*K + k0 + q4*8);
      *(uint4*)(Bs + row*40 + q4*8) = vb;
    }
    __syncthreads();
    v8s av[2], bv[8];
    #pragma unroll
    for (int mi=0;mi<2;mi++)
      av[mi] = *(const v8s*)(As + (wave*32 + mi*16 + r16)*40 + quad*8);
    #pragma unroll
    for (int ni=0;ni<8;ni++)
      bv[ni] = *(const v8s*)(Bs + (ni*16 + r16)*40 + quad*8);
    #pragma unroll
    for (int mi=0;mi<2;mi++)
      #pragma unroll
      for (int ni=0;ni<8;ni++)
        acc[mi][ni] = __builtin_amdgcn_mfma_f32_16x16x32_bf16(av[mi], bv[ni], acc[mi][ni], 0, 0, 0);
    __syncthreads();
  }

  #pragma unroll
  for (int mi=0;mi<2;mi++){
    #pragma unroll
    for (int r=0;r<4;r++){
      int row = m0 + wave*32 + mi*16 + quad*4 + r;
      if (row >= M) continue;
      #pragma unroll
      for (int ni=0;ni<8;ni++){
        int col = n0 + ni*16 + r16;
        float v = acc[mi][ni][r] + bias[col];
        if (ACT == 1) v = v > 0.f ? v : 0.f;
        C[(size_t)row*N + col] = __float2bfloat16(v);
      }
    }
  }
}

// ---------------------------------------------------------------------------
// CSR build
// ---------------------------------------------------------------------------
__global__ void deg_count_k(const int* __restrict__ dst, int* __restrict__ deg, int E){
  int e = blockIdx.x*256 + threadIdx.x;
  if (e < E){
    unsigned d = (unsigned)dst[e];
    if (d < (unsigned)NNODES) atomicAdd(&deg[d], 1);
  }
}

__global__ void scan_k(const int* __restrict__ deg, int* __restrict__ offs,
                       int* __restrict__ cursor, int n)
{
  __shared__ int part[256];
  __shared__ int base[256];
  int t = threadIdx.x;
  int lo = t*40, hi = lo+40;
  if (lo > n) lo = n;
  if (hi > n) hi = n;
  int s = 0;
  for (int i=lo;i<hi;i++) s += deg[i];
  part[t] = s;
  __syncthreads();
  if (t == 0){
    int run=0;
    for (int i=0;i<256;i++){ base[i]=run; run+=part[i]; }
    offs[n] = run;
  }
  __syncthreads();
  int run = base[t];
  for (int i=lo;i<hi;i++){ offs[i]=run; cursor[i]=run; run += deg[i]; }
}

__global__ void fill_k(const int* __restrict__ dst, int* __restrict__ cursor,
                       int* __restrict__ eids, int E){
  int e = blockIdx.x*256 + threadIdx.x;
  if (e < E){
    unsigned d = (unsigned)dst[e];
    if (d < (unsigned)NNODES){
      int p = atomicAdd(&cursor[d], 1);
      eids[p] = e;
    }
  }
}

// ---------------------------------------------------------------------------
// Fused GATv2 segment softmax + aggregation. 1 wave per dst node.
// xr[d] loaded once; sweep1 computes scores (max), sweep2 recomputes scores
// from the freshly-loaded xl fragment (deterministic) + exp-sum + weighted sum.
// ---------------------------------------------------------------------------
__global__ __launch_bounds__(256) void gat_sa(
    const int* __restrict__ offs, const int* __restrict__ eids, const int* __restrict__ src,
    const bf16* __restrict__ xc, const float* __restrict__ att,
    const float* __restrict__ gbias, bf16* __restrict__ agg)
{
  int d = blockIdx.x*4 + (threadIdx.x >> 6);
  if (d >= NNODES) return;
  int lane = threadIdx.x & 63;
  float fr[8];
  unpack8(*(const uint4*)(xc + (size_t)d*1024 + 512 + lane*8), fr);
  float4 a0 = *(const float4*)(att + lane*8);
  float4 a1 = *(const float4*)(att + lane*8 + 4);
  float fa[8] = {a0.x,a0.y,a0.z,a0.w,a1.x,a1.y,a1.z,a1.w};
  int i0 = offs[d], i1 = offs[d+1];

  float mx = -3.4e38f;
  for (int i=i0; i<i1; i++){
    int e = eids[i];
    unsigned s = (unsigned)src[e];
    if (s >= NNODES) s = 0;
    float fl[8];
    unpack8(*(const uint4*)(xc + (size_t)s*1024 + lane*8), fl);
    float p = 0.f;
    #pragma unroll
    for (int q=0;q<8;q++){
      float v = fl[q] + fr[q];
      v = v > 0.f ? v : 0.2f*v;
      p += v*fa[q];
    }
    p += __shfl_xor(p, 1); p += __shfl_xor(p, 2);
    p += __shfl_xor(p, 4); p += __shfl_xor(p, 8);
    mx = fmaxf(mx, p);
  }

  float den = 0.f;
  float acc[8] = {0,0,0,0,0,0,0,0};
  for (int i=i0; i<i1; i++){
    int e = eids[i];
    unsigned s = (unsigned)src[e];
    if (s >= NNODES) s = 0;
    float fl[8];
    unpack8(*(const uint4*)(xc + (size_t)s*1024 + lane*8), fl);
    float p = 0.f;
    #pragma unroll
    for (int q=0;q<8;q++){
      float v = fl[q] + fr[q];
      v = v > 0.f ? v : 0.2f*v;
      p += v*fa[q];
    }
    p += __shfl_xor(p, 1); p += __shfl_xor(p, 2);
    p += __shfl_xor(p, 4); p += __shfl_xor(p, 8);
    float w = __expf(p - mx);
    den += w;
    #pragma unroll
    for (int q=0;q<8;q++) acc[q] += w*fl[q];
  }
  float r = 1.f/(den + 1e-16f);
  float4 b0 = *(const float4*)(gbias + lane*8);
  float4 b1 = *(const float4*)(gbias + lane*8 + 4);
  float fb[8] = {b0.x,b0.y,b0.z,b0.w,b1.x,b1.y,b1.z,b1.w};
  #pragma unroll
  for (int q=0;q<8;q++)
    agg[(size_t)d*GDIM + lane*8 + q] = __float2bfloat16(acc[q]*r + fb[q]);
}

// ---------------------------------------------------------------------------
// Final linear (N=24): f32 weights, f32 out.
// ---------------------------------------------------------------------------
__global__ __launch_bounds__(256) void mlp_final_k(
    const bf16* __restrict__ a, const float* __restrict__ w,
    const float* __restrict__ b, float* __restrict__ out)
{
  int g = blockIdx.x*256 + threadIdx.x;
  if (g >= NNODES*24) return;
  int j = g % 24;
  int row = g / 24;
  const bf16* ar = a + (size_t)row*HID;
  const float* wr = w + (size_t)j*HID;
  float s = b[j];
  for (int k=0;k<HID;k+=8){
    float fa[8];
    unpack8(*(const uint4*)(ar+k), fa);
    float4 w0 = *(const float4*)(wr + k);
    float4 w1 = *(const float4*)(wr + k + 4);
    s += fa[0]*w0.x + fa[1]*w0.y + fa[2]*w0.z + fa[3]*w0.w
       + fa[4]*w1.x + fa[5]*w1.y + fa[6]*w1.z + fa[7]*w1.w;
  }
  out[g] = s;
}

// ---------------------------------------------------------------------------

extern "C" void kernel_launch(void* const* d_in, const int* in_sizes, int n_in,
                              void* d_out, int out_size, void* d_ws, size_t ws_size,
                              hipStream_t stream)
{
  const float* x   = (const float*)d_in[0];
  const int*   ei  = (const int*)d_in[1];
  const int E = in_sizes[1] / 2;
  const int* srcp = ei;
  const int* dstp = ei + E;

  const float* miw0 = (const float*)d_in[2];
  const float* mib0 = (const float*)d_in[3];
  const float* miw1 = (const float*)d_in[4];
  const float* mib1 = (const float*)d_in[5];
  const float* wih0 = (const float*)d_in[6];
  const float* whh0 = (const float*)d_in[7];
  const float* bih0 = (const float*)d_in[8];
  const float* bhh0 = (const float*)d_in[9];
  const float* wih1 = (const float*)d_in[10];
  const float* whh1 = (const float*)d_in[11];
  const float* bih1 = (const float*)d_in[12];
  const float* bhh1 = (const float*)d_in[13];
  const float* g_wl[2]   = {(const float*)d_in[14], (const float*)d_in[22]};
  const float* g_bl[2]   = {(const float*)d_in[15], (const float*)d_in[23]};
  const float* g_wr[2]   = {(const float*)d_in[16], (const float*)d_in[24]};
  const float* g_br[2]   = {(const float*)d_in[17], (const float*)d_in[25]};
  const float* g_att[2]  = {(const float*)d_in[18], (const float*)d_in[26]};
  const float* g_bias[2] = {(const float*)d_in[19], (const float*)d_in[27]};
  const float* g_pw[2]   = {(const float*)d_in[20], (const float*)d_in[28]};
  const float* g_pb[2]   = {(const float*)d_in[21], (const float*)d_in[29]};
  const float* mow0 = (const float*)d_in[30];
  const float* mob0 = (const float*)d_in[31];
  const float* mow1 = (const float*)d_in[32];
  const float* mob1 = (const float*)d_in[33];
  (void)n_in; (void)out_size; (void)ws_size;

  // ---- workspace layout (~92 MB) ----
  char* base = (char*)d_ws;
  size_t off = 0;
  auto carve = [&](size_t n)->char*{
    char* p = base + off;
    off = (off + n + 255) & ~(size_t)255;
    return p;
  };
  char*  X0r = carve((size_t)TLEN*NNODES*HID*2);   // 61,440,000
  bf16*  h1a = (bf16*)carve((size_t)NNODES*HID*2);
  bf16*  h1b = (bf16*)carve((size_t)NNODES*HID*2);
  bf16*  h2a = (bf16*)carve((size_t)NNODES*HID*2);
  bf16*  h2b = (bf16*)carve((size_t)NNODES*HID*2);
  bf16*  zb  = (bf16*)carve((size_t)NNODES*HID*2);
  float* cb1 = (float*)carve((size_t)NNODES*HID*4);
  float* cb2 = (float*)carve((size_t)NNODES*HID*4);
  float* Wp  = (float*)carve(HID*INDIM*4);
  float* bp  = (float*)carve(HID*4);
  float* bsum= (float*)carve(2*GDIM*4);
  float* gblr= (float*)carve(2*1024*4);
  bf16*  wbf = (bf16*)carve((size_t)671744*2);
  int*   offsb = (int*)carve((size_t)(NNODES+1)*4);
  int*   curs  = (int*)carve((size_t)NNODES*4);
  int*   eids  = (int*)carve((size_t)E*4);
  int*   deg   = (int*)carve((size_t)NNODES*4);
  bf16*  agg   = (bf16*)carve((size_t)NNODES*GDIM*2);

  // wbf sub-pointers (conv_w_k chunk order)
  const bf16* wih0b = wbf + 0;
  const bf16* whh0b = wbf + 65536;
  const bf16* wih1b = wbf + 131072;
  const bf16* whh1b = wbf + 196608;
  const bf16* wlr0b = wbf + 262144;   // wl0|wr0 contiguous [1024,128]
  const bf16* pw0b  = wbf + 393216;
  const bf16* wlr1b = wbf + 458752;   // wl1|wr1 contiguous
  const bf16* pw1b  = wbf + 589824;
  const bf16* mow0b = wbf + 655360;
  const bf16* wlrb[2] = {wlr0b, wlr1b};
  const bf16* pwb[2]  = {pw0b, pw1b};

  // X0 region aliases (dead after LSTM)
  bf16* X0 = (bf16*)X0r;
  bf16* xc = (bf16*)X0r;                      // [10000,1024] = xl|xr
  bf16* z2 = (bf16*)(X0r + 20480000);
  bf16* z3 = (bf16*)(X0r + 23040000);
  bf16* o0 = (bf16*)(X0r + 25600000);

  // ---- prep ----
  conv_w_k<<<2624, 256, 0, stream>>>(wih0, whh0, wih1, whh1,
                                     g_wl[0], g_wr[0], g_pw[0],
                                     g_wl[1], g_wr[1], g_pw[1], mow0, wbf);
  prep_w_k<<<1, 256, 0, stream>>>(miw0, mib0, miw1, mib1,
                                  bih0, bhh0, bih1, bhh1,
                                  g_bl[0], g_br[0], g_bl[1], g_br[1],
                                  Wp, bp, bsum, gblr);
  hipMemsetAsync(zb, 0, (size_t)NNODES*HID*2, stream);
  hipMemsetAsync(cb1, 0, (size_t)NNODES*HID*4, stream);
  hipMemsetAsync(cb2, 0, (size_t)NNODES*HID*4, stream);
  hipMemsetAsync(deg, 0, (size_t)NNODES*4, stream);

  // ---- MLP in ----
  mlp_in_k<<<(TLEN*NNODES)/8, 256, 0, stream>>>(x, Wp, bp, X0);

  // ---- CSR build ----
  deg_count_k<<<(E+255)/256, 256, 0, stream>>>(dstp, deg, E);
  scan_k<<<1, 256, 0, stream>>>(deg, offsb, curs, NNODES);
  fill_k<<<(E+255)/256, 256, 0, stream>>>(dstp, curs, eids, E);

  // ---- LSTM: both layers interleaved per timestep, no-LDS step kernel ----
  const int NBL = (NNODES + 31) / 32;   // 313
  for (int t=0; t<TLEN; t++){
    const bf16* Xt  = X0 + (size_t)t*NNODES*HID;
    const bf16* Hp1 = (t==0) ? zb : ((t & 1) ? h1a : h1b);
    bf16* Ho1 = (t & 1) ? h1b : h1a;
    lstm_step2<<<NBL, 256, 0, stream>>>(Xt, Hp1, wih0b, whh0b, bsum, cb1, Ho1);
    const bf16* Hp2 = (t==0) ? zb : ((t & 1) ? h2a : h2b);
    bf16* Ho2 = (t & 1) ? h2b : h2a;
    lstm_step2<<<NBL, 256, 0, stream>>>(Ho1, Hp2, wih1b, whh1b, bsum + GDIM, cb2, Ho2);
  }
  const bf16* z = h2b;   // t=23 (odd) wrote h2b

  // ---- GAT layers ----
  const bf16* zin = z;
  bf16* zouts[2] = {z2, z3};
  for (int l=0; l<2; l++){
    gemm_bt<0><<<dim3(79,8), 256, 0, stream>>>(zin, wlrb[l], gblr + l*1024, xc, NNODES, 1024, HID);
    gat_sa<<<(NNODES+3)/4, 256, 0, stream>>>(offsb, eids, srcp, xc, g_att[l], g_bias[l], agg);
    gemm_bt<1><<<dim3(79,1), 256, 0, stream>>>(agg, pwb[l], g_pb[l], zouts[l], NNODES, HID, GDIM);
    zin = zouts[l];
  }

  // ---- MLP out ----
  gemm_bt<1><<<dim3(79,1), 256, 0, stream>>>(z3, mow0b, mob0, o0, NNODES, HID, HID);
  mlp_final_k<<<(NNODES*24+255)/256, 256, 0, stream>>>(o0, mow1, mob1, (float*)d_out);
}

// Round 6
// 1351.820 us; speedup vs baseline: 3.2228x; 1.4541x over previous
//
#include <hip/hip_runtime.h>
#include <hip/hip_bf16.h>

#define NNODES 10000
#define TLEN 24
#define INDIM 16
#define HID 128
#define GDIM 512   // 4*HID (LSTM gates) == HEADS*HID (GAT)

typedef __hip_bfloat16 bf16;
typedef short v8s __attribute__((ext_vector_type(8)));
typedef float v4f __attribute__((ext_vector_type(4)));

__device__ inline float u2f(unsigned u){ return __uint_as_float(u); }

__device__ inline void unpack8(uint4 v, float* f){
  f[0]=u2f(v.x<<16); f[1]=u2f(v.x&0xFFFF0000u);
  f[2]=u2f(v.y<<16); f[3]=u2f(v.y&0xFFFF0000u);
  f[4]=u2f(v.z<<16); f[5]=u2f(v.z&0xFFFF0000u);
  f[6]=u2f(v.w<<16); f[7]=u2f(v.w&0xFFFF0000u);
}

__device__ inline float sigm(float x){ return 1.f/(1.f+__expf(-x)); }

// ---------------------------------------------------------------------------
// Convert 11 f32 weight matrices (MFMA B-operands) to bf16.
// Order: wih0,whh0,wih1,whh1, wl0,wr0,pw0, wl1,wr1,pw1 (65536 ea), mow0 (16384).
// ---------------------------------------------------------------------------
__global__ __launch_bounds__(256) void conv_w_k(
    const float* s0, const float* s1, const float* s2, const float* s3,
    const float* s4, const float* s5, const float* s6, const float* s7,
    const float* s8, const float* s9, const float* s10, bf16* __restrict__ dst)
{
  int idx = blockIdx.x*256 + threadIdx.x;
  if (idx >= 671744) return;
  int c = idx >> 16;
  float v;
  if (c < 10){
    const float* srcs[10] = {s0,s1,s2,s3,s4,s5,s6,s7,s8,s9};
    v = srcs[c][idx & 0xFFFF];
  } else {
    v = s10[idx - 655360];
  }
  dst[idx] = __float2bfloat16(v);
}

// ---------------------------------------------------------------------------
// Prep: folded MLP-in weights (f32), presummed LSTM biases, concat GAT biases.
// ---------------------------------------------------------------------------
__global__ void prep_w_k(
    const float* __restrict__ miw0, const float* __restrict__ mib0,
    const float* __restrict__ miw1, const float* __restrict__ mib1,
    const float* __restrict__ bih0, const float* __restrict__ bhh0,
    const float* __restrict__ bih1, const float* __restrict__ bhh1,
    const float* __restrict__ bl0, const float* __restrict__ br0,
    const float* __restrict__ bl1, const float* __restrict__ br1,
    float* __restrict__ Wp, float* __restrict__ bp,
    float* __restrict__ bsum, float* __restrict__ gblr)
{
  int t = threadIdx.x;
  for (int idx = t; idx < HID*INDIM; idx += 256){
    int j = idx >> 4, d = idx & 15;
    float s = 0.f;
    for (int k=0;k<HID;k++) s += miw1[j*HID+k] * miw0[k*INDIM+d];
    Wp[idx] = s;
  }
  for (int j = t; j < HID; j += 256){
    float s = mib1[j];
    for (int k=0;k<HID;k++) s += miw1[j*HID+k] * mib0[k];
    bp[j] = s;
  }
  for (int i = t; i < GDIM; i += 256){
    bsum[i]        = bih0[i] + bhh0[i];
    bsum[GDIM + i] = bih1[i] + bhh1[i];
  }
  for (int i = t; i < GDIM; i += 256){
    gblr[i]          = bl0[i];
    gblr[GDIM + i]   = br0[i];
    gblr[1024 + i]   = bl1[i];
    gblr[1536 + i]   = br1[i];
  }
}

// ---------------------------------------------------------------------------
// MLP-in v3: 64-row x-tile in LDS, W row in registers (j fixed per thread).
// Block: 256 thr = 2 row-phases x 128 j. Grid 3750.
// ---------------------------------------------------------------------------
__global__ __launch_bounds__(256) void mlp_in_k(
    const float* __restrict__ x, const float* __restrict__ Wp,
    const float* __restrict__ bp, bf16* __restrict__ X0)
{
  __shared__ __align__(16) float xs[64*16];
  const int tid = threadIdx.x;
  const int m0 = blockIdx.x*64;

  // stage: one float4 per thread (64 rows x 4 quads)
  {
    int row = tid >> 2, q = tid & 3;
    int m = m0 + row;
    int t = m / NNODES, n = m - t*NNODES;
    float4 v = *(const float4*)(x + ((size_t)n*TLEN + t)*INDIM + q*4);
    *(float4*)(xs + row*16 + q*4) = v;
  }

  const int j = tid & 127;
  const int half = tid >> 7;
  const float* wr = Wp + j*INDIM;
  float4 w0 = *(const float4*)(wr);
  float4 w1 = *(const float4*)(wr + 4);
  float4 w2 = *(const float4*)(wr + 8);
  float4 w3 = *(const float4*)(wr + 12);
  float bj = bp[j];
  __syncthreads();

  #pragma unroll 4
  for (int mi=0; mi<32; mi++){
    int row = mi*2 + half;
    const float* xr = xs + row*16;
    float4 a0 = *(const float4*)(xr);
    float4 a1 = *(const float4*)(xr + 4);
    float4 a2 = *(const float4*)(xr + 8);
    float4 a3 = *(const float4*)(xr + 12);
    float s = bj
      + a0.x*w0.x + a0.y*w0.y + a0.z*w0.z + a0.w*w0.w
      + a1.x*w1.x + a1.y*w1.y + a1.z*w1.z + a1.w*w1.w
      + a2.x*w2.x + a2.y*w2.y + a2.z*w2.z + a2.w*w2.w
      + a3.x*w3.x + a3.y*w3.y + a3.z*w3.z + a3.w*w3.w;
    s = s > 0.f ? s : 0.f;
    X0[(size_t)(m0+row)*HID + j] = __float2bfloat16(s);
  }
}

// ---------------------------------------------------------------------------
// Fused dual-layer LSTM step. Grid (79,4,2): z=layer. Layer 0 runs step t,
// layer 1 runs step t-1 (pipeline across disjoint blocks). 25 launches.
// Block (bx, cb) owns rows [128bx,+128) x hidden cols [32cb,+32) of all
// 4 gates (B staging gathers gate rows). LDS-staged (r3-proven body).
// ---------------------------------------------------------------------------
__global__ __launch_bounds__(256) void lstm_fused(
    const bf16* __restrict__ X0,
    bf16* __restrict__ h1a, bf16* __restrict__ h1b,
    bf16* __restrict__ h2a, bf16* __restrict__ h2b,
    const bf16* __restrict__ zb, const bf16* __restrict__ Wb,
    const float* __restrict__ bsum,
    float* __restrict__ cb1, float* __restrict__ cb2, int t)
{
  const int lay = blockIdx.z;
  if (lay == 0 && t == TLEN) return;
  if (lay == 1 && t == 0) return;
  const int step = lay ? t-1 : t;

  bf16* h1buf[2] = {h1a, h1b};
  bf16* h2buf[2] = {h2a, h2b};
  const bf16* Xp; const bf16* Hp; bf16* Ho;
  if (!lay){
    Xp = X0 + (size_t)step*NNODES*HID;
    Hp = step ? h1buf[(step-1)&1] : zb;
    Ho = h1buf[step&1];
  } else {
    Xp = h1buf[step&1];
    Hp = step ? h2buf[(step-1)&1] : zb;
    Ho = h2buf[step&1];
  }
  const bf16* Wih = Wb + (size_t)lay*131072;
  const bf16* Whh = Wih + 65536;
  float* cst = lay ? cb2 : cb1;

  __shared__ __align__(16) bf16 As[128*40];
  __shared__ __align__(16) bf16 Bs[128*40];
  const int tid = threadIdx.x;
  const int m0 = blockIdx.x*128;
  const int cb = blockIdx.y;
  const int lane = tid & 63, wave = tid >> 6;
  const int r16 = lane & 15, quad = lane >> 4;

  v4f acc[2][8];
  #pragma unroll
  for (int a=0;a<2;a++)
    #pragma unroll
    for (int b=0;b<8;b++) acc[a][b] = (v4f)0.f;

  #pragma unroll
  for (int ph=0; ph<2; ph++){
    const bf16* Ap = ph ? Hp : Xp;
    const bf16* Wq = ph ? Whh : Wih;
    for (int k0=0; k0<128; k0+=32){
      #pragma unroll
      for (int i=0;i<2;i++){
        int li = tid + i*256;
        int row = li >> 2, q4 = li & 3;
        uint4 va = make_uint4(0,0,0,0);
        int gm = m0 + row;
        if (gm < NNODES) va = *(const uint4*)(Ap + (size_t)gm*HID + k0 + q4*8);
        *(uint4*)(As + row*40 + q4*8) = va;
        int wr = ((row>>5)*HID) + cb*32 + (row & 31);
        uint4 vb = *(const uint4*)(Wq + (size_t)wr*HID + k0 + q4*8);
        *(uint4*)(Bs + row*40 + q4*8) = vb;
      }
      __syncthreads();
      v8s av[2], bv[8];
      #pragma unroll
      for (int mi=0;mi<2;mi++)
        av[mi] = *(const v8s*)(As + (wave*32 + mi*16 + r16)*40 + quad*8);
      #pragma unroll
      for (int ni=0;ni<8;ni++)
        bv[ni] = *(const v8s*)(Bs + (ni*16 + r16)*40 + quad*8);
      #pragma unroll
      for (int mi=0;mi<2;mi++)
        #pragma unroll
        for (int ni=0;ni<8;ni++)
          acc[mi][ni] = __builtin_amdgcn_mfma_f32_16x16x32_bf16(av[mi], bv[ni], acc[mi][ni], 0, 0, 0);
      __syncthreads();
    }
  }

  float bias_r[8];
  #pragma unroll
  for (int g=0; g<4; g++)
    #pragma unroll
    for (int half=0; half<2; half++)
      bias_r[g*2+half] = bsum[lay*GDIM + g*HID + cb*32 + half*16 + r16];

  #pragma unroll
  for (int mi=0;mi<2;mi++){
    #pragma unroll
    for (int r=0;r<4;r++){
      int row = m0 + wave*32 + mi*16 + quad*4 + r;
      if (row >= NNODES) continue;
      #pragma unroll
      for (int half=0; half<2; half++){
        int hcol = cb*32 + half*16 + r16;
        float iv = acc[mi][0+half][r] + bias_r[0+half];
        float fv = acc[mi][2+half][r] + bias_r[2+half];
        float gv = acc[mi][4+half][r] + bias_r[4+half];
        float ov = acc[mi][6+half][r] + bias_r[6+half];
        float ig = sigm(iv), fg = sigm(fv);
        float gg = tanhf(gv), og = sigm(ov);
        size_t ci = (size_t)row*HID + hcol;
        float cn = fg*cst[ci] + ig*gg;
        cst[ci] = cn;
        Ho[ci] = __float2bfloat16(og*tanhf(cn));
      }
    }
  }
}

// ---------------------------------------------------------------------------
// Generic bf16 GEMM: C[M,N] = act(A[M,K] @ B[N,K]^T + bias_f32[N]), bf16 out.
// ---------------------------------------------------------------------------
template<int ACT>
__global__ __launch_bounds__(256) void gemm_bt(
    const bf16* __restrict__ A, const bf16* __restrict__ B,
    const float* __restrict__ bias, bf16* __restrict__ C,
    int M, int N, int K)
{
  __shared__ __align__(16) bf16 As[128*40];
  __shared__ __align__(16) bf16 Bs[128*40];
  const int tid = threadIdx.x;
  const int m0 = blockIdx.x*128, n0 = blockIdx.y*128;
  const int lane = tid & 63, wave = tid >> 6;
  const int r16 = lane & 15, quad = lane >> 4;

  v4f acc[2][8];
  #pragma unroll
  for (int a=0;a<2;a++)
    #pragma unroll
    for (int b=0;b<8;b++) acc[a][b] = (v4f)0.f;

  for (int k0=0; k0<K; k0+=32){
    #pragma unroll
    for (int i=0;i<2;i++){
      int li = tid + i*256;
      int row = li >> 2, q4 = li & 3;
      uint4 va = make_uint4(0,0,0,0);
      int gm = m0 + row;
      if (gm < M) va = *(const uint4*)(A + (size_t)gm*K + k0 + q4*8);
      *(uint4*)(As + row*40 + q4*8) = va;
      uint4 vb = make_uint4(0,0,0,0);
      int gn = n0 + row;
      if (gn < N) vb = *(const uint4*)(B + (size_t)gn*K + k0 + q4*8);
      *(uint4*)(Bs + row*40 + q4*8) = vb;
    }
    __syncthreads();
    v8s av[2], bv[8];
    #pragma unroll
    for (int mi=0;mi<2;mi++)
      av[mi] = *(const v8s*)(As + (wave*32 + mi*16 + r16)*40 + quad*8);
    #pragma unroll
    for (int ni=0;ni<8;ni++)
      bv[ni] = *(const v8s*)(Bs + (ni*16 + r16)*40 + quad*8);
    #pragma unroll
    for (int mi=0;mi<2;mi++)
      #pragma unroll
      for (int ni=0;ni<8;ni++)
        acc[mi][ni] = __builtin_amdgcn_mfma_f32_16x16x32_bf16(av[mi], bv[ni], acc[mi][ni], 0, 0, 0);
    __syncthreads();
  }

  #pragma unroll
  for (int mi=0;mi<2;mi++){
    #pragma unroll
    for (int r=0;r<4;r++){
      int row = m0 + wave*32 + mi*16 + quad*4 + r;
      if (row >= M) continue;
      #pragma unroll
      for (int ni=0;ni<8;ni++){
        int col = n0 + ni*16 + r16;
        float v = acc[mi][ni][r] + bias[col];
        if (ACT == 1) v = v > 0.f ? v : 0.f;
        C[(size_t)row*N + col] = __float2bfloat16(v);
      }
    }
  }
}

// ---------------------------------------------------------------------------
// CSR build (payload = resolved src id)
// ---------------------------------------------------------------------------
__global__ void deg_count_k(const int* __restrict__ dst, int* __restrict__ deg, int E){
  int e = blockIdx.x*256 + threadIdx.x;
  if (e < E){
    unsigned d = (unsigned)dst[e];
    if (d < (unsigned)NNODES) atomicAdd(&deg[d], 1);
  }
}

__global__ void scan_k(const int* __restrict__ deg, int* __restrict__ offs,
                       int* __restrict__ cursor, int n)
{
  __shared__ int part[256];
  __shared__ int base[256];
  int t = threadIdx.x;
  int lo = t*40, hi = lo+40;
  if (lo > n) lo = n;
  if (hi > n) hi = n;
  int s = 0;
  for (int i=lo;i<hi;i++) s += deg[i];
  part[t] = s;
  __syncthreads();
  if (t == 0){
    int run=0;
    for (int i=0;i<256;i++){ base[i]=run; run+=part[i]; }
    offs[n] = run;
  }
  __syncthreads();
  int run = base[t];
  for (int i=lo;i<hi;i++){ offs[i]=run; cursor[i]=run; run += deg[i]; }
}

__global__ void fill_k(const int* __restrict__ src, const int* __restrict__ dst,
                       int* __restrict__ cursor, int* __restrict__ srcs, int E){
  int e = blockIdx.x*256 + threadIdx.x;
  if (e < E){
    unsigned d = (unsigned)dst[e];
    if (d < (unsigned)NNODES){
      int p = atomicAdd(&cursor[d], 1);
      unsigned s = (unsigned)src[e];
      srcs[p] = (s < (unsigned)NNODES) ? (int)s : 0;
    }
  }
}

// ---------------------------------------------------------------------------
// GATv2 online-softmax fused score+aggregate. 1 wave/dst node, ONE gather
// per edge (flash-style running max/denom/acc with rescale).
// ---------------------------------------------------------------------------
__global__ __launch_bounds__(256) void gat_onl(
    const int* __restrict__ offs, const int* __restrict__ srcs,
    const bf16* __restrict__ xc, const float* __restrict__ att,
    const float* __restrict__ gbias, bf16* __restrict__ agg)
{
  int d = blockIdx.x*4 + (threadIdx.x >> 6);
  if (d >= NNODES) return;
  int lane = threadIdx.x & 63;
  float fr[8];
  unpack8(*(const uint4*)(xc + (size_t)d*1024 + 512 + lane*8), fr);
  float4 a0 = *(const float4*)(att + lane*8);
  float4 a1 = *(const float4*)(att + lane*8 + 4);
  float fa[8] = {a0.x,a0.y,a0.z,a0.w,a1.x,a1.y,a1.z,a1.w};
  int i0 = offs[d], i1 = offs[d+1];

  float m = -3.4e38f, den = 0.f;
  float acc[8] = {0,0,0,0,0,0,0,0};
  for (int i=i0; i<i1; i++){
    int s = srcs[i];
    float fl[8];
    unpack8(*(const uint4*)(xc + (size_t)s*1024 + lane*8), fl);
    float p = 0.f;
    #pragma unroll
    for (int q=0;q<8;q++){
      float v = fl[q] + fr[q];
      v = v > 0.f ? v : 0.2f*v;
      p += v*fa[q];
    }
    p += __shfl_xor(p, 1); p += __shfl_xor(p, 2);
    p += __shfl_xor(p, 4); p += __shfl_xor(p, 8);
    float mn = fmaxf(m, p);
    float corr = __expf(m - mn);
    float w = __expf(p - mn);
    den = den*corr + w;
    #pragma unroll
    for (int q=0;q<8;q++) acc[q] = acc[q]*corr + w*fl[q];
    m = mn;
  }
  float r = 1.f/(den + 1e-16f);
  float4 b0 = *(const float4*)(gbias + lane*8);
  float4 b1 = *(const float4*)(gbias + lane*8 + 4);
  float fb[8] = {b0.x,b0.y,b0.z,b0.w,b1.x,b1.y,b1.z,b1.w};
  #pragma unroll
  for (int q=0;q<8;q++)
    agg[(size_t)d*GDIM + lane*8 + q] = __float2bfloat16(acc[q]*r + fb[q]);
}

// ---------------------------------------------------------------------------
// Final linear (N=24): f32 weights, f32 out.
// ---------------------------------------------------------------------------
__global__ __launch_bounds__(256) void mlp_final_k(
    const bf16* __restrict__ a, const float* __restrict__ w,
    const float* __restrict__ b, float* __restrict__ out)
{
  int g = blockIdx.x*256 + threadIdx.x;
  if (g >= NNODES*24) return;
  int j = g % 24;
  int row = g / 24;
  const bf16* ar = a + (size_t)row*HID;
  const float* wr = w + (size_t)j*HID;
  float s = b[j];
  for (int k=0;k<HID;k+=8){
    float fa[8];
    unpack8(*(const uint4*)(ar+k), fa);
    float4 w0 = *(const float4*)(wr + k);
    float4 w1 = *(const float4*)(wr + k + 4);
    s += fa[0]*w0.x + fa[1]*w0.y + fa[2]*w0.z + fa[3]*w0.w
       + fa[4]*w1.x + fa[5]*w1.y + fa[6]*w1.z + fa[7]*w1.w;
  }
  out[g] = s;
}

// ---------------------------------------------------------------------------

extern "C" void kernel_launch(void* const* d_in, const int* in_sizes, int n_in,
                              void* d_out, int out_size, void* d_ws, size_t ws_size,
                              hipStream_t stream)
{
  const float* x   = (const float*)d_in[0];
  const int*   ei  = (const int*)d_in[1];
  const int E = in_sizes[1] / 2;
  const int* srcp = ei;
  const int* dstp = ei + E;

  const float* miw0 = (const float*)d_in[2];
  const float* mib0 = (const float*)d_in[3];
  const float* miw1 = (const float*)d_in[4];
  const float* mib1 = (const float*)d_in[5];
  const float* wih0 = (const float*)d_in[6];
  const float* whh0 = (const float*)d_in[7];
  const float* bih0 = (const float*)d_in[8];
  const float* bhh0 = (const float*)d_in[9];
  const float* wih1 = (const float*)d_in[10];
  const float* whh1 = (const float*)d_in[11];
  const float* bih1 = (const float*)d_in[12];
  const float* bhh1 = (const float*)d_in[13];
  const float* g_wl[2]   = {(const float*)d_in[14], (const float*)d_in[22]};
  const float* g_bl[2]   = {(const float*)d_in[15], (const float*)d_in[23]};
  const float* g_wr[2]   = {(const float*)d_in[16], (const float*)d_in[24]};
  const float* g_br[2]   = {(const float*)d_in[17], (const float*)d_in[25]};
  const float* g_att[2]  = {(const float*)d_in[18], (const float*)d_in[26]};
  const float* g_bias[2] = {(const float*)d_in[19], (const float*)d_in[27]};
  const float* g_pw[2]   = {(const float*)d_in[20], (const float*)d_in[28]};
  const float* g_pb[2]   = {(const float*)d_in[21], (const float*)d_in[29]};
  const float* mow0 = (const float*)d_in[30];
  const float* mob0 = (const float*)d_in[31];
  const float* mow1 = (const float*)d_in[32];
  const float* mob1 = (const float*)d_in[33];
  (void)n_in; (void)out_size; (void)ws_size;

  // ---- workspace layout (~92 MB) ----
  char* base = (char*)d_ws;
  size_t off = 0;
  auto carve = [&](size_t n)->char*{
    char* p = base + off;
    off = (off + n + 255) & ~(size_t)255;
    return p;
  };
  char*  X0r = carve((size_t)TLEN*NNODES*HID*2);   // 61,440,000
  bf16*  h1a = (bf16*)carve((size_t)NNODES*HID*2);
  bf16*  h1b = (bf16*)carve((size_t)NNODES*HID*2);
  bf16*  h2a = (bf16*)carve((size_t)NNODES*HID*2);
  bf16*  h2b = (bf16*)carve((size_t)NNODES*HID*2);
  bf16*  zb  = (bf16*)carve((size_t)NNODES*HID*2);
  float* cb1 = (float*)carve((size_t)NNODES*HID*4);
  float* cb2 = (float*)carve((size_t)NNODES*HID*4);
  float* Wp  = (float*)carve(HID*INDIM*4);
  float* bp  = (float*)carve(HID*4);
  float* bsum= (float*)carve(2*GDIM*4);
  float* gblr= (float*)carve(2*1024*4);
  bf16*  wbf = (bf16*)carve((size_t)671744*2);
  int*   offsb = (int*)carve((size_t)(NNODES+1)*4);
  int*   curs  = (int*)carve((size_t)NNODES*4);
  int*   srcs  = (int*)carve((size_t)E*4);
  int*   deg   = (int*)carve((size_t)NNODES*4);
  bf16*  agg   = (bf16*)carve((size_t)NNODES*GDIM*2);

  // wbf sub-pointers (conv_w_k chunk order)
  const bf16* wlr0b = wbf + 262144;   // wl0|wr0 contiguous [1024,128]
  const bf16* pw0b  = wbf + 393216;
  const bf16* wlr1b = wbf + 458752;   // wl1|wr1 contiguous
  const bf16* pw1b  = wbf + 589824;
  const bf16* mow0b = wbf + 655360;
  const bf16* wlrb[2] = {wlr0b, wlr1b};
  const bf16* pwb[2]  = {pw0b, pw1b};

  // X0 region aliases (dead after LSTM)
  bf16* X0 = (bf16*)X0r;
  bf16* xc = (bf16*)X0r;                      // [10000,1024] = xl|xr
  bf16* z2 = (bf16*)(X0r + 20480000);
  bf16* z3 = (bf16*)(X0r + 23040000);
  bf16* o0 = (bf16*)(X0r + 25600000);

  // ---- prep ----
  conv_w_k<<<2624, 256, 0, stream>>>(wih0, whh0, wih1, whh1,
                                     g_wl[0], g_wr[0], g_pw[0],
                                     g_wl[1], g_wr[1], g_pw[1], mow0, wbf);
  prep_w_k<<<1, 256, 0, stream>>>(miw0, mib0, miw1, mib1,
                                  bih0, bhh0, bih1, bhh1,
                                  g_bl[0], g_br[0], g_bl[1], g_br[1],
                                  Wp, bp, bsum, gblr);
  hipMemsetAsync(zb, 0, (size_t)NNODES*HID*2, stream);
  hipMemsetAsync(cb1, 0, (size_t)NNODES*HID*4, stream);
  hipMemsetAsync(cb2, 0, (size_t)NNODES*HID*4, stream);
  hipMemsetAsync(deg, 0, (size_t)NNODES*4, stream);

  // ---- MLP in ----
  mlp_in_k<<<(TLEN*NNODES)/64, 256, 0, stream>>>(x, Wp, bp, X0);

  // ---- CSR build ----
  deg_count_k<<<(E+255)/256, 256, 0, stream>>>(dstp, deg, E);
  scan_k<<<1, 256, 0, stream>>>(deg, offsb, curs, NNODES);
  fill_k<<<(E+255)/256, 256, 0, stream>>>(srcp, dstp, curs, srcs, E);

  // ---- LSTM: fused dual-layer pipeline, 25 launches ----
  for (int t=0; t<=TLEN; t++)
    lstm_fused<<<dim3(79,4,2), 256, 0, stream>>>(X0, h1a, h1b, h2a, h2b,
                                                 zb, wbf, bsum, cb1, cb2, t);
  const bf16* z = h2b;   // step 23 wrote h2buf[1]

  // ---- GAT layers ----
  const bf16* zin = z;
  bf16* zouts[2] = {z2, z3};
  for (int l=0; l<2; l++){
    gemm_bt<0><<<dim3(79,8), 256, 0, stream>>>(zin, wlrb[l], gblr + l*1024, xc, NNODES, 1024, HID);
    gat_onl<<<(NNODES+3)/4, 256, 0, stream>>>(offsb, srcs, xc, g_att[l], g_bias[l], agg);
    gemm_bt<1><<<dim3(79,1), 256, 0, stream>>>(agg, pwb[l], g_pb[l], zouts[l], NNODES, HID, GDIM);
    zin = zouts[l];
  }

  // ---- MLP out ----
  gemm_bt<1><<<dim3(79,1), 256, 0, stream>>>(z3, mow0b, mob0, o0, NNODES, HID, HID);
  mlp_final_k<<<(NNODES*24+255)/256, 256, 0, stream>>>(o0, mow1, mob1, (float*)d_out);
}

// Round 7
// 1275.131 us; speedup vs baseline: 3.4166x; 1.0601x over previous
//
#include <hip/hip_runtime.h>
#include <hip/hip_bf16.h>

#define NNODES 10000
#define TLEN 24
#define INDIM 16
#define HID 128
#define GDIM 512   // 4*HID (LSTM gates) == HEADS*HID (GAT)

typedef __hip_bfloat16 bf16;
typedef short v8s __attribute__((ext_vector_type(8)));
typedef float v4f __attribute__((ext_vector_type(4)));

__device__ inline float u2f(unsigned u){ return __uint_as_float(u); }

__device__ inline void unpack8(uint4 v, float* f){
  f[0]=u2f(v.x<<16); f[1]=u2f(v.x&0xFFFF0000u);
  f[2]=u2f(v.y<<16); f[3]=u2f(v.y&0xFFFF0000u);
  f[4]=u2f(v.z<<16); f[5]=u2f(v.z&0xFFFF0000u);
  f[6]=u2f(v.w<<16); f[7]=u2f(v.w&0xFFFF0000u);
}

__device__ inline float sigm(float x){ return 1.f/(1.f+__expf(-x)); }

// ---------------------------------------------------------------------------
// Convert 11 f32 weight matrices (MFMA B-operands) to bf16.
// Order: wih0,whh0,wih1,whh1, wl0,wr0,pw0, wl1,wr1,pw1 (65536 ea), mow0 (16384).
// ---------------------------------------------------------------------------
__global__ __launch_bounds__(256) void conv_w_k(
    const float* s0, const float* s1, const float* s2, const float* s3,
    const float* s4, const float* s5, const float* s6, const float* s7,
    const float* s8, const float* s9, const float* s10, bf16* __restrict__ dst)
{
  int idx = blockIdx.x*256 + threadIdx.x;
  if (idx >= 671744) return;
  int c = idx >> 16;
  float v;
  if (c < 10){
    const float* srcs[10] = {s0,s1,s2,s3,s4,s5,s6,s7,s8,s9};
    v = srcs[c][idx & 0xFFFF];
  } else {
    v = s10[idx - 655360];
  }
  dst[idx] = __float2bfloat16(v);
}

// ---------------------------------------------------------------------------
// Prep: folded MLP-in weights (f32), presummed LSTM biases, concat GAT biases.
// ---------------------------------------------------------------------------
__global__ void prep_w_k(
    const float* __restrict__ miw0, const float* __restrict__ mib0,
    const float* __restrict__ miw1, const float* __restrict__ mib1,
    const float* __restrict__ bih0, const float* __restrict__ bhh0,
    const float* __restrict__ bih1, const float* __restrict__ bhh1,
    const float* __restrict__ bl0, const float* __restrict__ br0,
    const float* __restrict__ bl1, const float* __restrict__ br1,
    float* __restrict__ Wp, float* __restrict__ bp,
    float* __restrict__ bsum, float* __restrict__ gblr)
{
  int t = threadIdx.x;
  for (int idx = t; idx < HID*INDIM; idx += 256){
    int j = idx >> 4, d = idx & 15;
    float s = 0.f;
    for (int k=0;k<HID;k++) s += miw1[j*HID+k] * miw0[k*INDIM+d];
    Wp[idx] = s;
  }
  for (int j = t; j < HID; j += 256){
    float s = mib1[j];
    for (int k=0;k<HID;k++) s += miw1[j*HID+k] * mib0[k];
    bp[j] = s;
  }
  for (int i = t; i < GDIM; i += 256){
    bsum[i]        = bih0[i] + bhh0[i];
    bsum[GDIM + i] = bih1[i] + bhh1[i];
  }
  for (int i = t; i < GDIM; i += 256){
    gblr[i]          = bl0[i];
    gblr[GDIM + i]   = br0[i];
    gblr[1024 + i]   = bl1[i];
    gblr[1536 + i]   = br1[i];
  }
}

// ---------------------------------------------------------------------------
// MLP-in: 64-row x-tile in LDS, W row in registers. Grid 3750.
// ---------------------------------------------------------------------------
__global__ __launch_bounds__(256) void mlp_in_k(
    const float* __restrict__ x, const float* __restrict__ Wp,
    const float* __restrict__ bp, bf16* __restrict__ X0)
{
  __shared__ __align__(16) float xs[64*16];
  const int tid = threadIdx.x;
  const int m0 = blockIdx.x*64;
  {
    int row = tid >> 2, q = tid & 3;
    int m = m0 + row;
    int t = m / NNODES, n = m - t*NNODES;
    float4 v = *(const float4*)(x + ((size_t)n*TLEN + t)*INDIM + q*4);
    *(float4*)(xs + row*16 + q*4) = v;
  }
  const int j = tid & 127;
  const int half = tid >> 7;
  const float* wr = Wp + j*INDIM;
  float4 w0 = *(const float4*)(wr);
  float4 w1 = *(const float4*)(wr + 4);
  float4 w2 = *(const float4*)(wr + 8);
  float4 w3 = *(const float4*)(wr + 12);
  float bj = bp[j];
  __syncthreads();
  #pragma unroll 4
  for (int mi=0; mi<32; mi++){
    int row = mi*2 + half;
    const float* xr = xs + row*16;
    float4 a0 = *(const float4*)(xr);
    float4 a1 = *(const float4*)(xr + 4);
    float4 a2 = *(const float4*)(xr + 8);
    float4 a3 = *(const float4*)(xr + 12);
    float s = bj
      + a0.x*w0.x + a0.y*w0.y + a0.z*w0.z + a0.w*w0.w
      + a1.x*w1.x + a1.y*w1.y + a1.z*w1.z + a1.w*w1.w
      + a2.x*w2.x + a2.y*w2.y + a2.z*w2.z + a2.w*w2.w
      + a3.x*w3.x + a3.y*w3.y + a3.z*w3.z + a3.w*w3.w;
    s = s > 0.f ? s : 0.f;
    X0[(size_t)(m0+row)*HID + j] = __float2bfloat16(s);
  }
}

// ---------------------------------------------------------------------------
// Single-launch LSTM: recurrence is row-local, so each block owns 32 rows
// and runs all 24 steps x 2 layers with h in LDS and c in registers.
// Wave w owns hidden cols [32w,32w+32) of all 4 gates. Weights stream from
// L2 (512KB, re-read per step). Only global I/O: X0 read once, z written.
// LDS h rows padded to 136 elems (272B) -> 2-way bank aliasing (free).
// ---------------------------------------------------------------------------
__global__ __launch_bounds__(256) void lstm_seq(
    const bf16* __restrict__ X0, const bf16* __restrict__ Wb,
    const float* __restrict__ bsum, bf16* __restrict__ z)
{
  __shared__ __align__(16) bf16 h1s[32*136];
  __shared__ __align__(16) bf16 h2s[32*136];
  const int tid = threadIdx.x;
  const int lane = tid & 63, wave = tid >> 6;
  const int r16 = lane & 15, quad = lane >> 4;
  const int m0 = blockIdx.x*32;

  // zero h state (t=0 initial condition)
  for (int i = tid; i < 32*136; i += 256){ h1s[i] = __float2bfloat16(0.f); h2s[i] = __float2bfloat16(0.f); }

  const bf16* Wih0 = Wb;
  const bf16* Whh0 = Wb + 65536;
  const bf16* Wih1 = Wb + 131072;
  const bf16* Whh1 = Wb + 196608;

  // B-row offsets (elements), constant across steps: ni = g*2+half
  int boff[8];
  #pragma unroll
  for (int g=0; g<4; g++)
    #pragma unroll
    for (int hf=0; hf<2; hf++)
      boff[g*2+hf] = (g*HID + wave*32 + hf*16 + r16) * HID;

  float bias1[8], bias2[8];
  #pragma unroll
  for (int g=0; g<4; g++)
    #pragma unroll
    for (int hf=0; hf<2; hf++){
      bias1[g*2+hf] = bsum[       g*HID + wave*32 + hf*16 + r16];
      bias2[g*2+hf] = bsum[GDIM + g*HID + wave*32 + hf*16 + r16];
    }

  // clamped global A-rows for X loads
  int xrow[2];
  #pragma unroll
  for (int mi=0; mi<2; mi++){
    int r = m0 + mi*16 + r16;
    xrow[mi] = r < NNODES ? r : NNODES-1;
  }

  float c1[16], c2[16];   // [mi*8 + r*2 + half]
  #pragma unroll
  for (int i=0;i<16;i++){ c1[i]=0.f; c2[i]=0.f; }

  __syncthreads();

  for (int t=0; t<TLEN; t++){
    // ================= layer 1 =================
    {
      v4f acc[2][8];
      #pragma unroll
      for (int a=0;a<2;a++)
        #pragma unroll
        for (int b=0;b<8;b++) acc[a][b] = (v4f)0.f;

      const bf16* Xt = X0 + (size_t)t*NNODES*HID;
      #pragma unroll
      for (int k0=0; k0<128; k0+=32){           // ih: A from global X
        v8s av[2], bv[8];
        av[0] = *(const v8s*)(Xt + (size_t)xrow[0]*HID + k0 + quad*8);
        av[1] = *(const v8s*)(Xt + (size_t)xrow[1]*HID + k0 + quad*8);
        #pragma unroll
        for (int ni=0;ni<8;ni++)
          bv[ni] = *(const v8s*)(Wih0 + boff[ni] + k0 + quad*8);
        #pragma unroll
        for (int mi=0;mi<2;mi++)
          #pragma unroll
          for (int ni=0;ni<8;ni++)
            acc[mi][ni] = __builtin_amdgcn_mfma_f32_16x16x32_bf16(av[mi], bv[ni], acc[mi][ni], 0, 0, 0);
      }
      #pragma unroll
      for (int k0=0; k0<128; k0+=32){           // hh: A from LDS h1
        v8s av[2], bv[8];
        av[0] = *(const v8s*)(h1s + (     r16)*136 + k0 + quad*8);
        av[1] = *(const v8s*)(h1s + (16 + r16)*136 + k0 + quad*8);
        #pragma unroll
        for (int ni=0;ni<8;ni++)
          bv[ni] = *(const v8s*)(Whh0 + boff[ni] + k0 + quad*8);
        #pragma unroll
        for (int mi=0;mi<2;mi++)
          #pragma unroll
          for (int ni=0;ni<8;ni++)
            acc[mi][ni] = __builtin_amdgcn_mfma_f32_16x16x32_bf16(av[mi], bv[ni], acc[mi][ni], 0, 0, 0);
      }
      __syncthreads();   // all reads of h1s done
      #pragma unroll
      for (int mi=0;mi<2;mi++)
        #pragma unroll
        for (int r=0;r<4;r++){
          int lrow = mi*16 + quad*4 + r;
          #pragma unroll
          for (int hf=0; hf<2; hf++){
            float iv = acc[mi][0+hf][r] + bias1[0+hf];
            float fv = acc[mi][2+hf][r] + bias1[2+hf];
            float gv = acc[mi][4+hf][r] + bias1[4+hf];
            float ov = acc[mi][6+hf][r] + bias1[6+hf];
            float ig = sigm(iv), fg = sigm(fv);
            float gg = tanhf(gv), og = sigm(ov);
            int ci = mi*8 + r*2 + hf;
            float cn = fg*c1[ci] + ig*gg;
            c1[ci] = cn;
            h1s[lrow*136 + wave*32 + hf*16 + r16] = __float2bfloat16(og*tanhf(cn));
          }
        }
      __syncthreads();   // h1[t] visible
    }
    // ================= layer 2 =================
    {
      v4f acc[2][8];
      #pragma unroll
      for (int a=0;a<2;a++)
        #pragma unroll
        for (int b=0;b<8;b++) acc[a][b] = (v4f)0.f;

      #pragma unroll
      for (int k0=0; k0<128; k0+=32){           // ih: A = h1[t] (LDS)
        v8s av[2], bv[8];
        av[0] = *(const v8s*)(h1s + (     r16)*136 + k0 + quad*8);
        av[1] = *(const v8s*)(h1s + (16 + r16)*136 + k0 + quad*8);
        #pragma unroll
        for (int ni=0;ni<8;ni++)
          bv[ni] = *(const v8s*)(Wih1 + boff[ni] + k0 + quad*8);
        #pragma unroll
        for (int mi=0;mi<2;mi++)
          #pragma unroll
          for (int ni=0;ni<8;ni++)
            acc[mi][ni] = __builtin_amdgcn_mfma_f32_16x16x32_bf16(av[mi], bv[ni], acc[mi][ni], 0, 0, 0);
      }
      #pragma unroll
      for (int k0=0; k0<128; k0+=32){           // hh: A = h2[t-1] (LDS)
        v8s av[2], bv[8];
        av[0] = *(const v8s*)(h2s + (     r16)*136 + k0 + quad*8);
        av[1] = *(const v8s*)(h2s + (16 + r16)*136 + k0 + quad*8);
        #pragma unroll
        for (int ni=0;ni<8;ni++)
          bv[ni] = *(const v8s*)(Whh1 + boff[ni] + k0 + quad*8);
        #pragma unroll
        for (int mi=0;mi<2;mi++)
          #pragma unroll
          for (int ni=0;ni<8;ni++)
            acc[mi][ni] = __builtin_amdgcn_mfma_f32_16x16x32_bf16(av[mi], bv[ni], acc[mi][ni], 0, 0, 0);
      }
      __syncthreads();   // all reads of h1s/h2s done
      #pragma unroll
      for (int mi=0;mi<2;mi++)
        #pragma unroll
        for (int r=0;r<4;r++){
          int lrow = mi*16 + quad*4 + r;
          #pragma unroll
          for (int hf=0; hf<2; hf++){
            float iv = acc[mi][0+hf][r] + bias2[0+hf];
            float fv = acc[mi][2+hf][r] + bias2[2+hf];
            float gv = acc[mi][4+hf][r] + bias2[4+hf];
            float ov = acc[mi][6+hf][r] + bias2[6+hf];
            float ig = sigm(iv), fg = sigm(fv);
            float gg = tanhf(gv), og = sigm(ov);
            int ci = mi*8 + r*2 + hf;
            float cn = fg*c2[ci] + ig*gg;
            c2[ci] = cn;
            h2s[lrow*136 + wave*32 + hf*16 + r16] = __float2bfloat16(og*tanhf(cn));
          }
        }
      __syncthreads();   // h2[t] visible
    }
  }

  // write z = h2[23]: 256 thr x 16 cols
  {
    int lrow = tid >> 3;
    int cg = (tid & 7) * 16;
    int grow = m0 + lrow;
    if (grow < NNODES){
      uint4 v0 = *(const uint4*)(h2s + lrow*136 + cg);
      uint4 v1 = *(const uint4*)(h2s + lrow*136 + cg + 8);
      *(uint4*)(z + (size_t)grow*HID + cg)     = v0;
      *(uint4*)(z + (size_t)grow*HID + cg + 8) = v1;
    }
  }
}

// ---------------------------------------------------------------------------
// Generic bf16 GEMM: C[M,N] = act(A[M,K] @ B[N,K]^T + bias_f32[N]), bf16 out.
// ---------------------------------------------------------------------------
template<int ACT>
__global__ __launch_bounds__(256) void gemm_bt(
    const bf16* __restrict__ A, const bf16* __restrict__ B,
    const float* __restrict__ bias, bf16* __restrict__ C,
    int M, int N, int K)
{
  __shared__ __align__(16) bf16 As[128*40];
  __shared__ __align__(16) bf16 Bs[128*40];
  const int tid = threadIdx.x;
  const int m0 = blockIdx.x*128, n0 = blockIdx.y*128;
  const int lane = tid & 63, wave = tid >> 6;
  const int r16 = lane & 15, quad = lane >> 4;

  v4f acc[2][8];
  #pragma unroll
  for (int a=0;a<2;a++)
    #pragma unroll
    for (int b=0;b<8;b++) acc[a][b] = (v4f)0.f;

  for (int k0=0; k0<K; k0+=32){
    #pragma unroll
    for (int i=0;i<2;i++){
      int li = tid + i*256;
      int row = li >> 2, q4 = li & 3;
      uint4 va = make_uint4(0,0,0,0);
      int gm = m0 + row;
      if (gm < M) va = *(const uint4*)(A + (size_t)gm*K + k0 + q4*8);
      *(uint4*)(As + row*40 + q4*8) = va;
      uint4 vb = make_uint4(0,0,0,0);
      int gn = n0 + row;
      if (gn < N) vb = *(const uint4*)(B + (size_t)gn*K + k0 + q4*8);
      *(uint4*)(Bs + row*40 + q4*8) = vb;
    }
    __syncthreads();
    v8s av[2], bv[8];
    #pragma unroll
    for (int mi=0;mi<2;mi++)
      av[mi] = *(const v8s*)(As + (wave*32 + mi*16 + r16)*40 + quad*8);
    #pragma unroll
    for (int ni=0;ni<8;ni++)
      bv[ni] = *(const v8s*)(Bs + (ni*16 + r16)*40 + quad*8);
    #pragma unroll
    for (int mi=0;mi<2;mi++)
      #pragma unroll
      for (int ni=0;ni<8;ni++)
        acc[mi][ni] = __builtin_amdgcn_mfma_f32_16x16x32_bf16(av[mi], bv[ni], acc[mi][ni], 0, 0, 0);
    __syncthreads();
  }

  #pragma unroll
  for (int mi=0;mi<2;mi++){
    #pragma unroll
    for (int r=0;r<4;r++){
      int row = m0 + wave*32 + mi*16 + quad*4 + r;
      if (row >= M) continue;
      #pragma unroll
      for (int ni=0;ni<8;ni++){
        int col = n0 + ni*16 + r16;
        float v = acc[mi][ni][r] + bias[col];
        if (ACT == 1) v = v > 0.f ? v : 0.f;
        C[(size_t)row*N + col] = __float2bfloat16(v);
      }
    }
  }
}

// ---------------------------------------------------------------------------
// CSR build (payload = resolved src id)
// ---------------------------------------------------------------------------
__global__ void deg_count_k(const int* __restrict__ dst, int* __restrict__ deg, int E){
  int e = blockIdx.x*256 + threadIdx.x;
  if (e < E){
    unsigned d = (unsigned)dst[e];
    if (d < (unsigned)NNODES) atomicAdd(&deg[d], 1);
  }
}

__global__ void scan_k(const int* __restrict__ deg, int* __restrict__ offs,
                       int* __restrict__ cursor, int n)
{
  __shared__ int part[256];
  __shared__ int base[256];
  int t = threadIdx.x;
  int lo = t*40, hi = lo+40;
  if (lo > n) lo = n;
  if (hi > n) hi = n;
  int s = 0;
  for (int i=lo;i<hi;i++) s += deg[i];
  part[t] = s;
  __syncthreads();
  if (t == 0){
    int run=0;
    for (int i=0;i<256;i++){ base[i]=run; run+=part[i]; }
    offs[n] = run;
  }
  __syncthreads();
  int run = base[t];
  for (int i=lo;i<hi;i++){ offs[i]=run; cursor[i]=run; run += deg[i]; }
}

__global__ void fill_k(const int* __restrict__ src, const int* __restrict__ dst,
                       int* __restrict__ cursor, int* __restrict__ srcs, int E){
  int e = blockIdx.x*256 + threadIdx.x;
  if (e < E){
    unsigned d = (unsigned)dst[e];
    if (d < (unsigned)NNODES){
      int p = atomicAdd(&cursor[d], 1);
      unsigned s = (unsigned)src[e];
      srcs[p] = (s < (unsigned)NNODES) ? (int)s : 0;
    }
  }
}

// ---------------------------------------------------------------------------
// GATv2 online-softmax fused score+aggregate. 1 wave/dst node.
// ---------------------------------------------------------------------------
__global__ __launch_bounds__(256) void gat_onl(
    const int* __restrict__ offs, const int* __restrict__ srcs,
    const bf16* __restrict__ xc, const float* __restrict__ att,
    const float* __restrict__ gbias, bf16* __restrict__ agg)
{
  int d = blockIdx.x*4 + (threadIdx.x >> 6);
  if (d >= NNODES) return;
  int lane = threadIdx.x & 63;
  float fr[8];
  unpack8(*(const uint4*)(xc + (size_t)d*1024 + 512 + lane*8), fr);
  float4 a0 = *(const float4*)(att + lane*8);
  float4 a1 = *(const float4*)(att + lane*8 + 4);
  float fa[8] = {a0.x,a0.y,a0.z,a0.w,a1.x,a1.y,a1.z,a1.w};
  int i0 = offs[d], i1 = offs[d+1];

  float m = -3.4e38f, den = 0.f;
  float acc[8] = {0,0,0,0,0,0,0,0};
  for (int i=i0; i<i1; i++){
    int s = srcs[i];
    float fl[8];
    unpack8(*(const uint4*)(xc + (size_t)s*1024 + lane*8), fl);
    float p = 0.f;
    #pragma unroll
    for (int q=0;q<8;q++){
      float v = fl[q] + fr[q];
      v = v > 0.f ? v : 0.2f*v;
      p += v*fa[q];
    }
    p += __shfl_xor(p, 1); p += __shfl_xor(p, 2);
    p += __shfl_xor(p, 4); p += __shfl_xor(p, 8);
    float mn = fmaxf(m, p);
    float corr = __expf(m - mn);
    float w = __expf(p - mn);
    den = den*corr + w;
    #pragma unroll
    for (int q=0;q<8;q++) acc[q] = acc[q]*corr + w*fl[q];
    m = mn;
  }
  float r = 1.f/(den + 1e-16f);
  float4 b0 = *(const float4*)(gbias + lane*8);
  float4 b1 = *(const float4*)(gbias + lane*8 + 4);
  float fb[8] = {b0.x,b0.y,b0.z,b0.w,b1.x,b1.y,b1.z,b1.w};
  #pragma unroll
  for (int q=0;q<8;q++)
    agg[(size_t)d*GDIM + lane*8 + q] = __float2bfloat16(acc[q]*r + fb[q]);
}

// ---------------------------------------------------------------------------
// Final linear (N=24): f32 weights, f32 out.
// ---------------------------------------------------------------------------
__global__ __launch_bounds__(256) void mlp_final_k(
    const bf16* __restrict__ a, const float* __restrict__ w,
    const float* __restrict__ b, float* __restrict__ out)
{
  int g = blockIdx.x*256 + threadIdx.x;
  if (g >= NNODES*24) return;
  int j = g % 24;
  int row = g / 24;
  const bf16* ar = a + (size_t)row*HID;
  const float* wr = w + (size_t)j*HID;
  float s = b[j];
  for (int k=0;k<HID;k+=8){
    float fa[8];
    unpack8(*(const uint4*)(ar+k), fa);
    float4 w0 = *(const float4*)(wr + k);
    float4 w1 = *(const float4*)(wr + k + 4);
    s += fa[0]*w0.x + fa[1]*w0.y + fa[2]*w0.z + fa[3]*w0.w
       + fa[4]*w1.x + fa[5]*w1.y + fa[6]*w1.z + fa[7]*w1.w;
  }
  out[g] = s;
}

// ---------------------------------------------------------------------------

extern "C" void kernel_launch(void* const* d_in, const int* in_sizes, int n_in,
                              void* d_out, int out_size, void* d_ws, size_t ws_size,
                              hipStream_t stream)
{
  const float* x   = (const float*)d_in[0];
  const int*   ei  = (const int*)d_in[1];
  const int E = in_sizes[1] / 2;
  const int* srcp = ei;
  const int* dstp = ei + E;

  const float* miw0 = (const float*)d_in[2];
  const float* mib0 = (const float*)d_in[3];
  const float* miw1 = (const float*)d_in[4];
  const float* mib1 = (const float*)d_in[5];
  const float* wih0 = (const float*)d_in[6];
  const float* whh0 = (const float*)d_in[7];
  const float* bih0 = (const float*)d_in[8];
  const float* bhh0 = (const float*)d_in[9];
  const float* wih1 = (const float*)d_in[10];
  const float* whh1 = (const float*)d_in[11];
  const float* bih1 = (const float*)d_in[12];
  const float* bhh1 = (const float*)d_in[13];
  const float* g_wl[2]   = {(const float*)d_in[14], (const float*)d_in[22]};
  const float* g_bl[2]   = {(const float*)d_in[15], (const float*)d_in[23]};
  const float* g_wr[2]   = {(const float*)d_in[16], (const float*)d_in[24]};
  const float* g_br[2]   = {(const float*)d_in[17], (const float*)d_in[25]};
  const float* g_att[2]  = {(const float*)d_in[18], (const float*)d_in[26]};
  const float* g_bias[2] = {(const float*)d_in[19], (const float*)d_in[27]};
  const float* g_pw[2]   = {(const float*)d_in[20], (const float*)d_in[28]};
  const float* g_pb[2]   = {(const float*)d_in[21], (const float*)d_in[29]};
  const float* mow0 = (const float*)d_in[30];
  const float* mob0 = (const float*)d_in[31];
  const float* mow1 = (const float*)d_in[32];
  const float* mob1 = (const float*)d_in[33];
  (void)n_in; (void)out_size; (void)ws_size;

  // ---- workspace layout ----
  char* base = (char*)d_ws;
  size_t off = 0;
  auto carve = [&](size_t n)->char*{
    char* p = base + off;
    off = (off + n + 255) & ~(size_t)255;
    return p;
  };
  char*  X0r = carve((size_t)TLEN*NNODES*HID*2);   // 61,440,000
  bf16*  zf  = (bf16*)carve((size_t)NNODES*HID*2);
  float* Wp  = (float*)carve(HID*INDIM*4);
  float* bp  = (float*)carve(HID*4);
  float* bsum= (float*)carve(2*GDIM*4);
  float* gblr= (float*)carve(2*1024*4);
  bf16*  wbf = (bf16*)carve((size_t)671744*2);
  int*   offsb = (int*)carve((size_t)(NNODES+1)*4);
  int*   curs  = (int*)carve((size_t)NNODES*4);
  int*   srcs  = (int*)carve((size_t)E*4);
  int*   deg   = (int*)carve((size_t)NNODES*4);
  bf16*  agg   = (bf16*)carve((size_t)NNODES*GDIM*2);

  // wbf sub-pointers (conv_w_k chunk order)
  const bf16* wlr0b = wbf + 262144;   // wl0|wr0 contiguous [1024,128]
  const bf16* pw0b  = wbf + 393216;
  const bf16* wlr1b = wbf + 458752;   // wl1|wr1 contiguous
  const bf16* pw1b  = wbf + 589824;
  const bf16* mow0b = wbf + 655360;
  const bf16* wlrb[2] = {wlr0b, wlr1b};
  const bf16* pwb[2]  = {pw0b, pw1b};

  // X0 region aliases (dead after LSTM)
  bf16* X0 = (bf16*)X0r;
  bf16* xc = (bf16*)X0r;                      // [10000,1024] = xl|xr
  bf16* z2 = (bf16*)(X0r + 20480000);
  bf16* z3 = (bf16*)(X0r + 23040000);
  bf16* o0 = (bf16*)(X0r + 25600000);

  // ---- prep ----
  conv_w_k<<<2624, 256, 0, stream>>>(wih0, whh0, wih1, whh1,
                                     g_wl[0], g_wr[0], g_pw[0],
                                     g_wl[1], g_wr[1], g_pw[1], mow0, wbf);
  prep_w_k<<<1, 256, 0, stream>>>(miw0, mib0, miw1, mib1,
                                  bih0, bhh0, bih1, bhh1,
                                  g_bl[0], g_br[0], g_bl[1], g_br[1],
                                  Wp, bp, bsum, gblr);
  hipMemsetAsync(deg, 0, (size_t)NNODES*4, stream);

  // ---- MLP in ----
  mlp_in_k<<<(TLEN*NNODES)/64, 256, 0, stream>>>(x, Wp, bp, X0);

  // ---- CSR build ----
  deg_count_k<<<(E+255)/256, 256, 0, stream>>>(dstp, deg, E);
  scan_k<<<1, 256, 0, stream>>>(deg, offsb, curs, NNODES);
  fill_k<<<(E+255)/256, 256, 0, stream>>>(srcp, dstp, curs, srcs, E);

  // ---- LSTM: ONE launch, all 24 steps x 2 layers (row-local recurrence) ----
  lstm_seq<<<(NNODES+31)/32, 256, 0, stream>>>(X0, wbf, bsum, zf);

  // ---- GAT layers ----
  const bf16* zin = zf;
  bf16* zouts[2] = {z2, z3};
  for (int l=0; l<2; l++){
    gemm_bt<0><<<dim3(79,8), 256, 0, stream>>>(zin, wlrb[l], gblr + l*1024, xc, NNODES, 1024, HID);
    gat_onl<<<(NNODES+3)/4, 256, 0, stream>>>(offsb, srcs, xc, g_att[l], g_bias[l], agg);
    gemm_bt<1><<<dim3(79,1), 256, 0, stream>>>(agg, pwb[l], g_pb[l], zouts[l], NNODES, HID, GDIM);
    zin = zouts[l];
  }

  // ---- MLP out ----
  gemm_bt<1><<<dim3(79,1), 256, 0, stream>>>(z3, mow0b, mob0, o0, NNODES, HID, HID);
  mlp_final_k<<<(NNODES*24+255)/256, 256, 0, stream>>>(o0, mow1, mob1, (float*)d_out);
}

// Round 8
// 790.467 us; speedup vs baseline: 5.5115x; 1.6131x over previous
//
#include <hip/hip_runtime.h>
#include <hip/hip_bf16.h>

#define NNODES 10000
#define TLEN 24
#define INDIM 16
#define HID 128
#define GDIM 512   // 4*HID (LSTM gates) == HEADS*HID (GAT)

typedef __hip_bfloat16 bf16;
typedef short v8s __attribute__((ext_vector_type(8)));
typedef float v4f __attribute__((ext_vector_type(4)));

__device__ inline float u2f(unsigned u){ return __uint_as_float(u); }

__device__ inline void unpack8(uint4 v, float* f){
  f[0]=u2f(v.x<<16); f[1]=u2f(v.x&0xFFFF0000u);
  f[2]=u2f(v.y<<16); f[3]=u2f(v.y&0xFFFF0000u);
  f[4]=u2f(v.z<<16); f[5]=u2f(v.z&0xFFFF0000u);
  f[6]=u2f(v.w<<16); f[7]=u2f(v.w&0xFFFF0000u);
}

__device__ inline float sigm(float x){ return 1.f/(1.f+__expf(-x)); }

// ---------------------------------------------------------------------------
// Convert 11 f32 weight matrices (MFMA B-operands) to bf16.
// Order: wih0,whh0,wih1,whh1, wl0,wr0,pw0, wl1,wr1,pw1 (65536 ea), mow0 (16384).
// ---------------------------------------------------------------------------
__global__ __launch_bounds__(256) void conv_w_k(
    const float* s0, const float* s1, const float* s2, const float* s3,
    const float* s4, const float* s5, const float* s6, const float* s7,
    const float* s8, const float* s9, const float* s10, bf16* __restrict__ dst)
{
  int idx = blockIdx.x*256 + threadIdx.x;
  if (idx >= 671744) return;
  int c = idx >> 16;
  float v;
  if (c < 10){
    const float* srcs[10] = {s0,s1,s2,s3,s4,s5,s6,s7,s8,s9};
    v = srcs[c][idx & 0xFFFF];
  } else {
    v = s10[idx - 655360];
  }
  dst[idx] = __float2bfloat16(v);
}

// ---------------------------------------------------------------------------
// Prep: folded MLP-in weights (f32), presummed LSTM biases, concat GAT biases.
// ---------------------------------------------------------------------------
__global__ void prep_w_k(
    const float* __restrict__ miw0, const float* __restrict__ mib0,
    const float* __restrict__ miw1, const float* __restrict__ mib1,
    const float* __restrict__ bih0, const float* __restrict__ bhh0,
    const float* __restrict__ bih1, const float* __restrict__ bhh1,
    const float* __restrict__ bl0, const float* __restrict__ br0,
    const float* __restrict__ bl1, const float* __restrict__ br1,
    float* __restrict__ Wp, float* __restrict__ bp,
    float* __restrict__ bsum, float* __restrict__ gblr)
{
  int t = threadIdx.x;
  for (int idx = t; idx < HID*INDIM; idx += 256){
    int j = idx >> 4, d = idx & 15;
    float s = 0.f;
    for (int k=0;k<HID;k++) s += miw1[j*HID+k] * miw0[k*INDIM+d];
    Wp[idx] = s;
  }
  for (int j = t; j < HID; j += 256){
    float s = mib1[j];
    for (int k=0;k<HID;k++) s += miw1[j*HID+k] * mib0[k];
    bp[j] = s;
  }
  for (int i = t; i < GDIM; i += 256){
    bsum[i]        = bih0[i] + bhh0[i];
    bsum[GDIM + i] = bih1[i] + bhh1[i];
  }
  for (int i = t; i < GDIM; i += 256){
    gblr[i]          = bl0[i];
    gblr[GDIM + i]   = br0[i];
    gblr[1024 + i]   = bl1[i];
    gblr[1536 + i]   = br1[i];
  }
}

// ---------------------------------------------------------------------------
// MLP-in: 64-row x-tile in LDS, W row in registers. Grid 3750.
// ---------------------------------------------------------------------------
__global__ __launch_bounds__(256) void mlp_in_k(
    const float* __restrict__ x, const float* __restrict__ Wp,
    const float* __restrict__ bp, bf16* __restrict__ X0)
{
  __shared__ __align__(16) float xs[64*16];
  const int tid = threadIdx.x;
  const int m0 = blockIdx.x*64;
  {
    int row = tid >> 2, q = tid & 3;
    int m = m0 + row;
    int t = m / NNODES, n = m - t*NNODES;
    float4 v = *(const float4*)(x + ((size_t)n*TLEN + t)*INDIM + q*4);
    *(float4*)(xs + row*16 + q*4) = v;
  }
  const int j = tid & 127;
  const int half = tid >> 7;
  const float* wr = Wp + j*INDIM;
  float4 w0 = *(const float4*)(wr);
  float4 w1 = *(const float4*)(wr + 4);
  float4 w2 = *(const float4*)(wr + 8);
  float4 w3 = *(const float4*)(wr + 12);
  float bj = bp[j];
  __syncthreads();
  #pragma unroll 4
  for (int mi=0; mi<32; mi++){
    int row = mi*2 + half;
    const float* xr = xs + row*16;
    float4 a0 = *(const float4*)(xr);
    float4 a1 = *(const float4*)(xr + 4);
    float4 a2 = *(const float4*)(xr + 8);
    float4 a3 = *(const float4*)(xr + 12);
    float s = bj
      + a0.x*w0.x + a0.y*w0.y + a0.z*w0.z + a0.w*w0.w
      + a1.x*w1.x + a1.y*w1.y + a1.z*w1.z + a1.w*w1.w
      + a2.x*w2.x + a2.y*w2.y + a2.z*w2.z + a2.w*w2.w
      + a3.x*w3.x + a3.y*w3.y + a3.z*w3.z + a3.w*w3.w;
    s = s > 0.f ? s : 0.f;
    X0[(size_t)(m0+row)*HID + j] = __float2bfloat16(s);
  }
}

// ---------------------------------------------------------------------------
// LSTM, one layer for all 24 steps, weights REGISTER-RESIDENT.
// Block: 512 thr = 8 waves; wave w owns hidden cols [16w,16w+16) of all 4
// gates -> its Wih/Whh slice = 4 gates x 4 k-chunks x 16B/lane = 128 VGPRs,
// loaded once before the t-loop (zero weight traffic in-loop).
// Block owns 48 rows; h in LDS (48x136), c in 12 registers/lane.
// WRITE_ALL=1: write h[t] IN-PLACE over Xin[t] (block touches only its own
// rows -> no cross-block hazard). WRITE_ALL=0: write only final h to out.
// ---------------------------------------------------------------------------
template<int WRITE_ALL>
__global__ __launch_bounds__(512, 2) void lstm_half(
    const bf16* __restrict__ Xin, const bf16* __restrict__ Wih,
    const bf16* __restrict__ Whh, const float* __restrict__ bias,
    bf16* __restrict__ out)
{
  __shared__ __align__(16) bf16 hs[48*136];
  const int tid = threadIdx.x;
  const int lane = tid & 63, w = tid >> 6;
  const int r16 = lane & 15, quad = lane >> 4;
  const int m0 = blockIdx.x*48;

  // weights -> registers (once)
  v8s wbi[4][4], wbh[4][4];
  #pragma unroll
  for (int g=0; g<4; g++)
    #pragma unroll
    for (int kc=0; kc<4; kc++){
      size_t o = (size_t)(g*HID + w*16 + r16)*HID + kc*32 + quad*8;
      wbi[g][kc] = *(const v8s*)(Wih + o);
      wbh[g][kc] = *(const v8s*)(Whh + o);
    }
  float bg[4];
  #pragma unroll
  for (int g=0; g<4; g++) bg[g] = bias[g*HID + w*16 + r16];

  // clamped A-row offsets
  size_t rowoff[3];
  #pragma unroll
  for (int mi=0; mi<3; mi++){
    int r = m0 + mi*16 + r16;
    rowoff[mi] = (size_t)(r < NNODES ? r : NNODES-1) * HID;
  }

  float c[12];
  #pragma unroll
  for (int i=0;i<12;i++) c[i] = 0.f;

  // zero h state
  for (int i = tid; i < 816; i += 512)
    *(uint4*)((char*)hs + i*16) = make_uint4(0,0,0,0);
  __syncthreads();

  for (int t=0; t<TLEN; t++){
    const bf16* Xt = Xin + (size_t)t*NNODES*HID;

    v4f acc[3][4];
    #pragma unroll
    for (int mi=0;mi<3;mi++)
      #pragma unroll
      for (int g=0;g<4;g++) acc[mi][g] = (v4f)0.f;

    #pragma unroll
    for (int kc=0; kc<4; kc++){            // ih: A from global Xin[t]
      v8s av[3];
      #pragma unroll
      for (int mi=0;mi<3;mi++)
        av[mi] = *(const v8s*)(Xt + rowoff[mi] + kc*32 + quad*8);
      #pragma unroll
      for (int mi=0;mi<3;mi++)
        #pragma unroll
        for (int g=0;g<4;g++)
          acc[mi][g] = __builtin_amdgcn_mfma_f32_16x16x32_bf16(av[mi], wbi[g][kc], acc[mi][g], 0, 0, 0);
    }
    #pragma unroll
    for (int kc=0; kc<4; kc++){            // hh: A from LDS h[t-1]
      v8s av[3];
      #pragma unroll
      for (int mi=0;mi<3;mi++)
        av[mi] = *(const v8s*)(hs + (mi*16 + r16)*136 + kc*32 + quad*8);
      #pragma unroll
      for (int mi=0;mi<3;mi++)
        #pragma unroll
        for (int g=0;g<4;g++)
          acc[mi][g] = __builtin_amdgcn_mfma_f32_16x16x32_bf16(av[mi], wbh[g][kc], acc[mi][g], 0, 0, 0);
    }
    __syncthreads();   // all reads of hs (and Xt rows) complete

    #pragma unroll
    for (int mi=0;mi<3;mi++)
      #pragma unroll
      for (int r=0;r<4;r++){
        int lrow = mi*16 + quad*4 + r;
        float iv = acc[mi][0][r] + bg[0];
        float fv = acc[mi][1][r] + bg[1];
        float gv = acc[mi][2][r] + bg[2];
        float ov = acc[mi][3][r] + bg[3];
        float ig = sigm(iv), fg = sigm(fv);
        float gg = tanhf(gv), og = sigm(ov);
        int ci = mi*4 + r;
        float cn = fg*c[ci] + ig*gg;
        c[ci] = cn;
        hs[lrow*136 + w*16 + r16] = __float2bfloat16(og*tanhf(cn));
      }
    __syncthreads();   // h[t] visible

    if (WRITE_ALL){
      bf16* dst = (bf16*)Xt;   // in-place over consumed X rows (own rows only)
      for (int i = tid; i < 768; i += 512){
        int row = i >> 4, c8 = (i & 15) * 8;
        if (m0 + row < NNODES)
          *(uint4*)(dst + (size_t)(m0+row)*HID + c8) = *(const uint4*)(hs + row*136 + c8);
      }
      // next epilogue write to hs is guarded by next step's post-MFMA sync
    }
  }

  if (!WRITE_ALL){
    for (int i = tid; i < 768; i += 512){
      int row = i >> 4, c8 = (i & 15) * 8;
      if (m0 + row < NNODES)
        *(uint4*)(out + (size_t)(m0+row)*HID + c8) = *(const uint4*)(hs + row*136 + c8);
    }
  }
}

// ---------------------------------------------------------------------------
// Generic bf16 GEMM: C[M,N] = act(A[M,K] @ B[N,K]^T + bias_f32[N]), bf16 out.
// ---------------------------------------------------------------------------
template<int ACT>
__global__ __launch_bounds__(256) void gemm_bt(
    const bf16* __restrict__ A, const bf16* __restrict__ B,
    const float* __restrict__ bias, bf16* __restrict__ C,
    int M, int N, int K)
{
  __shared__ __align__(16) bf16 As[128*40];
  __shared__ __align__(16) bf16 Bs[128*40];
  const int tid = threadIdx.x;
  const int m0 = blockIdx.x*128, n0 = blockIdx.y*128;
  const int lane = tid & 63, wave = tid >> 6;
  const int r16 = lane & 15, quad = lane >> 4;

  v4f acc[2][8];
  #pragma unroll
  for (int a=0;a<2;a++)
    #pragma unroll
    for (int b=0;b<8;b++) acc[a][b] = (v4f)0.f;

  for (int k0=0; k0<K; k0+=32){
    #pragma unroll
    for (int i=0;i<2;i++){
      int li = tid + i*256;
      int row = li >> 2, q4 = li & 3;
      uint4 va = make_uint4(0,0,0,0);
      int gm = m0 + row;
      if (gm < M) va = *(const uint4*)(A + (size_t)gm*K + k0 + q4*8);
      *(uint4*)(As + row*40 + q4*8) = va;
      uint4 vb = make_uint4(0,0,0,0);
      int gn = n0 + row;
      if (gn < N) vb = *(const uint4*)(B + (size_t)gn*K + k0 + q4*8);
      *(uint4*)(Bs + row*40 + q4*8) = vb;
    }
    __syncthreads();
    v8s av[2], bv[8];
    #pragma unroll
    for (int mi=0;mi<2;mi++)
      av[mi] = *(const v8s*)(As + (wave*32 + mi*16 + r16)*40 + quad*8);
    #pragma unroll
    for (int ni=0;ni<8;ni++)
      bv[ni] = *(const v8s*)(Bs + (ni*16 + r16)*40 + quad*8);
    #pragma unroll
    for (int mi=0;mi<2;mi++)
      #pragma unroll
      for (int ni=0;ni<8;ni++)
        acc[mi][ni] = __builtin_amdgcn_mfma_f32_16x16x32_bf16(av[mi], bv[ni], acc[mi][ni], 0, 0, 0);
    __syncthreads();
  }

  #pragma unroll
  for (int mi=0;mi<2;mi++){
    #pragma unroll
    for (int r=0;r<4;r++){
      int row = m0 + wave*32 + mi*16 + quad*4 + r;
      if (row >= M) continue;
      #pragma unroll
      for (int ni=0;ni<8;ni++){
        int col = n0 + ni*16 + r16;
        float v = acc[mi][ni][r] + bias[col];
        if (ACT == 1) v = v > 0.f ? v : 0.f;
        C[(size_t)row*N + col] = __float2bfloat16(v);
      }
    }
  }
}

// ---------------------------------------------------------------------------
// CSR build (payload = resolved src id)
// ---------------------------------------------------------------------------
__global__ void deg_count_k(const int* __restrict__ dst, int* __restrict__ deg, int E){
  int e = blockIdx.x*256 + threadIdx.x;
  if (e < E){
    unsigned d = (unsigned)dst[e];
    if (d < (unsigned)NNODES) atomicAdd(&deg[d], 1);
  }
}

__global__ void scan_k(const int* __restrict__ deg, int* __restrict__ offs,
                       int* __restrict__ cursor, int n)
{
  __shared__ int part[256];
  __shared__ int base[256];
  int t = threadIdx.x;
  int lo = t*40, hi = lo+40;
  if (lo > n) lo = n;
  if (hi > n) hi = n;
  int s = 0;
  for (int i=lo;i<hi;i++) s += deg[i];
  part[t] = s;
  __syncthreads();
  if (t == 0){
    int run=0;
    for (int i=0;i<256;i++){ base[i]=run; run+=part[i]; }
    offs[n] = run;
  }
  __syncthreads();
  int run = base[t];
  for (int i=lo;i<hi;i++){ offs[i]=run; cursor[i]=run; run += deg[i]; }
}

__global__ void fill_k(const int* __restrict__ src, const int* __restrict__ dst,
                       int* __restrict__ cursor, int* __restrict__ srcs, int E){
  int e = blockIdx.x*256 + threadIdx.x;
  if (e < E){
    unsigned d = (unsigned)dst[e];
    if (d < (unsigned)NNODES){
      int p = atomicAdd(&cursor[d], 1);
      unsigned s = (unsigned)src[e];
      srcs[p] = (s < (unsigned)NNODES) ? (int)s : 0;
    }
  }
}

// ---------------------------------------------------------------------------
// GATv2 online-softmax fused score+aggregate. 1 wave/dst node.
// ---------------------------------------------------------------------------
__global__ __launch_bounds__(256) void gat_onl(
    const int* __restrict__ offs, const int* __restrict__ srcs,
    const bf16* __restrict__ xc, const float* __restrict__ att,
    const float* __restrict__ gbias, bf16* __restrict__ agg)
{
  int d = blockIdx.x*4 + (threadIdx.x >> 6);
  if (d >= NNODES) return;
  int lane = threadIdx.x & 63;
  float fr[8];
  unpack8(*(const uint4*)(xc + (size_t)d*1024 + 512 + lane*8), fr);
  float4 a0 = *(const float4*)(att + lane*8);
  float4 a1 = *(const float4*)(att + lane*8 + 4);
  float fa[8] = {a0.x,a0.y,a0.z,a0.w,a1.x,a1.y,a1.z,a1.w};
  int i0 = offs[d], i1 = offs[d+1];

  float m = -3.4e38f, den = 0.f;
  float acc[8] = {0,0,0,0,0,0,0,0};
  for (int i=i0; i<i1; i++){
    int s = srcs[i];
    float fl[8];
    unpack8(*(const uint4*)(xc + (size_t)s*1024 + lane*8), fl);
    float p = 0.f;
    #pragma unroll
    for (int q=0;q<8;q++){
      float v = fl[q] + fr[q];
      v = v > 0.f ? v : 0.2f*v;
      p += v*fa[q];
    }
    p += __shfl_xor(p, 1); p += __shfl_xor(p, 2);
    p += __shfl_xor(p, 4); p += __shfl_xor(p, 8);
    float mn = fmaxf(m, p);
    float corr = __expf(m - mn);
    float w = __expf(p - mn);
    den = den*corr + w;
    #pragma unroll
    for (int q=0;q<8;q++) acc[q] = acc[q]*corr + w*fl[q];
    m = mn;
  }
  float r = 1.f/(den + 1e-16f);
  float4 b0 = *(const float4*)(gbias + lane*8);
  float4 b1 = *(const float4*)(gbias + lane*8 + 4);
  float fb[8] = {b0.x,b0.y,b0.z,b0.w,b1.x,b1.y,b1.z,b1.w};
  #pragma unroll
  for (int q=0;q<8;q++)
    agg[(size_t)d*GDIM + lane*8 + q] = __float2bfloat16(acc[q]*r + fb[q]);
}

// ---------------------------------------------------------------------------
// Final linear (N=24): f32 weights, f32 out.
// ---------------------------------------------------------------------------
__global__ __launch_bounds__(256) void mlp_final_k(
    const bf16* __restrict__ a, const float* __restrict__ w,
    const float* __restrict__ b, float* __restrict__ out)
{
  int g = blockIdx.x*256 + threadIdx.x;
  if (g >= NNODES*24) return;
  int j = g % 24;
  int row = g / 24;
  const bf16* ar = a + (size_t)row*HID;
  const float* wr = w + (size_t)j*HID;
  float s = b[j];
  for (int k=0;k<HID;k+=8){
    float fa[8];
    unpack8(*(const uint4*)(ar+k), fa);
    float4 w0 = *(const float4*)(wr + k);
    float4 w1 = *(const float4*)(wr + k + 4);
    s += fa[0]*w0.x + fa[1]*w0.y + fa[2]*w0.z + fa[3]*w0.w
       + fa[4]*w1.x + fa[5]*w1.y + fa[6]*w1.z + fa[7]*w1.w;
  }
  out[g] = s;
}

// ---------------------------------------------------------------------------

extern "C" void kernel_launch(void* const* d_in, const int* in_sizes, int n_in,
                              void* d_out, int out_size, void* d_ws, size_t ws_size,
                              hipStream_t stream)
{
  const float* x   = (const float*)d_in[0];
  const int*   ei  = (const int*)d_in[1];
  const int E = in_sizes[1] / 2;
  const int* srcp = ei;
  const int* dstp = ei + E;

  const float* miw0 = (const float*)d_in[2];
  const float* mib0 = (const float*)d_in[3];
  const float* miw1 = (const float*)d_in[4];
  const float* mib1 = (const float*)d_in[5];
  const float* wih0 = (const float*)d_in[6];
  const float* whh0 = (const float*)d_in[7];
  const float* bih0 = (const float*)d_in[8];
  const float* bhh0 = (const float*)d_in[9];
  const float* wih1 = (const float*)d_in[10];
  const float* whh1 = (const float*)d_in[11];
  const float* bih1 = (const float*)d_in[12];
  const float* bhh1 = (const float*)d_in[13];
  const float* g_wl[2]   = {(const float*)d_in[14], (const float*)d_in[22]};
  const float* g_bl[2]   = {(const float*)d_in[15], (const float*)d_in[23]};
  const float* g_wr[2]   = {(const float*)d_in[16], (const float*)d_in[24]};
  const float* g_br[2]   = {(const float*)d_in[17], (const float*)d_in[25]};
  const float* g_att[2]  = {(const float*)d_in[18], (const float*)d_in[26]};
  const float* g_bias[2] = {(const float*)d_in[19], (const float*)d_in[27]};
  const float* g_pw[2]   = {(const float*)d_in[20], (const float*)d_in[28]};
  const float* g_pb[2]   = {(const float*)d_in[21], (const float*)d_in[29]};
  const float* mow0 = (const float*)d_in[30];
  const float* mob0 = (const float*)d_in[31];
  const float* mow1 = (const float*)d_in[32];
  const float* mob1 = (const float*)d_in[33];
  (void)n_in; (void)out_size; (void)ws_size;

  // ---- workspace layout ----
  char* base = (char*)d_ws;
  size_t off = 0;
  auto carve = [&](size_t n)->char*{
    char* p = base + off;
    off = (off + n + 255) & ~(size_t)255;
    return p;
  };
  char*  X0r = carve((size_t)TLEN*NNODES*HID*2);   // 61,440,000
  bf16*  zf  = (bf16*)carve((size_t)NNODES*HID*2);
  float* Wp  = (float*)carve(HID*INDIM*4);
  float* bp  = (float*)carve(HID*4);
  float* bsum= (float*)carve(2*GDIM*4);
  float* gblr= (float*)carve(2*1024*4);
  bf16*  wbf = (bf16*)carve((size_t)671744*2);
  int*   offsb = (int*)carve((size_t)(NNODES+1)*4);
  int*   curs  = (int*)carve((size_t)NNODES*4);
  int*   srcs  = (int*)carve((size_t)E*4);
  int*   deg   = (int*)carve((size_t)NNODES*4);
  bf16*  agg   = (bf16*)carve((size_t)NNODES*GDIM*2);

  // wbf sub-pointers (conv_w_k chunk order)
  const bf16* wih0b = wbf + 0;
  const bf16* whh0b = wbf + 65536;
  const bf16* wih1b = wbf + 131072;
  const bf16* whh1b = wbf + 196608;
  const bf16* wlr0b = wbf + 262144;   // wl0|wr0 contiguous [1024,128]
  const bf16* pw0b  = wbf + 393216;
  const bf16* wlr1b = wbf + 458752;   // wl1|wr1 contiguous
  const bf16* pw1b  = wbf + 589824;
  const bf16* mow0b = wbf + 655360;
  const bf16* wlrb[2] = {wlr0b, wlr1b};
  const bf16* pwb[2]  = {pw0b, pw1b};

  // X0 region aliases (holds X0, then h1 in-place, dead after LSTM)
  bf16* X0 = (bf16*)X0r;
  bf16* xc = (bf16*)X0r;                      // [10000,1024] = xl|xr
  bf16* z2 = (bf16*)(X0r + 20480000);
  bf16* z3 = (bf16*)(X0r + 23040000);
  bf16* o0 = (bf16*)(X0r + 25600000);

  // ---- prep ----
  conv_w_k<<<2624, 256, 0, stream>>>(wih0, whh0, wih1, whh1,
                                     g_wl[0], g_wr[0], g_pw[0],
                                     g_wl[1], g_wr[1], g_pw[1], mow0, wbf);
  prep_w_k<<<1, 256, 0, stream>>>(miw0, mib0, miw1, mib1,
                                  bih0, bhh0, bih1, bhh1,
                                  g_bl[0], g_br[0], g_bl[1], g_br[1],
                                  Wp, bp, bsum, gblr);
  hipMemsetAsync(deg, 0, (size_t)NNODES*4, stream);

  // ---- MLP in ----
  mlp_in_k<<<(TLEN*NNODES)/64, 256, 0, stream>>>(x, Wp, bp, X0);

  // ---- CSR build ----
  deg_count_k<<<(E+255)/256, 256, 0, stream>>>(dstp, deg, E);
  scan_k<<<1, 256, 0, stream>>>(deg, offsb, curs, NNODES);
  fill_k<<<(E+255)/256, 256, 0, stream>>>(srcp, dstp, curs, srcs, E);

  // ---- LSTM: layer 1 (writes h1[t] in-place over X0), then layer 2 ----
  const int NBL = (NNODES + 47) / 48;   // 209 blocks = 1/CU
  lstm_half<1><<<NBL, 512, 0, stream>>>(X0, wih0b, whh0b, bsum, nullptr);
  lstm_half<0><<<NBL, 512, 0, stream>>>(X0, wih1b, whh1b, bsum + GDIM, zf);

  // ---- GAT layers ----
  const bf16* zin = zf;
  bf16* zouts[2] = {z2, z3};
  for (int l=0; l<2; l++){
    gemm_bt<0><<<dim3(79,8), 256, 0, stream>>>(zin, wlrb[l], gblr + l*1024, xc, NNODES, 1024, HID);
    gat_onl<<<(NNODES+3)/4, 256, 0, stream>>>(offsb, srcs, xc, g_att[l], g_bias[l], agg);
    gemm_bt<1><<<dim3(79,1), 256, 0, stream>>>(agg, pwb[l], g_pb[l], zouts[l], NNODES, HID, GDIM);
    zin = zouts[l];
  }

  // ---- MLP out ----
  gemm_bt<1><<<dim3(79,1), 256, 0, stream>>>(z3, mow0b, mob0, o0, NNODES, HID, HID);
  mlp_final_k<<<(NNODES*24+255)/256, 256, 0, stream>>>(o0, mow1, mob1, (float*)d_out);
}

// Round 9
// 714.500 us; speedup vs baseline: 6.0975x; 1.1063x over previous
//
#include <hip/hip_runtime.h>
#include <hip/hip_bf16.h>

#define NNODES 10000
#define TLEN 24
#define INDIM 16
#define HID 128
#define GDIM 512   // 4*HID (LSTM gates) == HEADS*HID (GAT)

typedef __hip_bfloat16 bf16;
typedef short v8s __attribute__((ext_vector_type(8)));
typedef float v4f __attribute__((ext_vector_type(4)));

__device__ inline float u2f(unsigned u){ return __uint_as_float(u); }

__device__ inline void unpack8(uint4 v, float* f){
  f[0]=u2f(v.x<<16); f[1]=u2f(v.x&0xFFFF0000u);
  f[2]=u2f(v.y<<16); f[3]=u2f(v.y&0xFFFF0000u);
  f[4]=u2f(v.z<<16); f[5]=u2f(v.z&0xFFFF0000u);
  f[6]=u2f(v.w<<16); f[7]=u2f(v.w&0xFFFF0000u);
}

__device__ inline float sigm(float x){ return 1.f/(1.f+__expf(-x)); }

// fast device transcendentals (v_exp_f32 + v_rcp_f32; inf-safe)
__device__ inline float fsig(float x){
  return __builtin_amdgcn_rcpf(1.f + __expf(-x));
}
__device__ inline float ftanh(float x){
  float t = __expf(-2.f*fabsf(x));           // in (0,1], no overflow
  float r = (1.f - t) * __builtin_amdgcn_rcpf(1.f + t);
  return copysignf(r, x);
}

// ---------------------------------------------------------------------------
// Convert 11 f32 weight matrices (MFMA B-operands) to bf16.
// Order: wih0,whh0,wih1,whh1, wl0,wr0,pw0, wl1,wr1,pw1 (65536 ea), mow0 (16384).
// ---------------------------------------------------------------------------
__global__ __launch_bounds__(256) void conv_w_k(
    const float* s0, const float* s1, const float* s2, const float* s3,
    const float* s4, const float* s5, const float* s6, const float* s7,
    const float* s8, const float* s9, const float* s10, bf16* __restrict__ dst)
{
  int idx = blockIdx.x*256 + threadIdx.x;
  if (idx >= 671744) return;
  int c = idx >> 16;
  float v;
  if (c < 10){
    const float* srcs[10] = {s0,s1,s2,s3,s4,s5,s6,s7,s8,s9};
    v = srcs[c][idx & 0xFFFF];
  } else {
    v = s10[idx - 655360];
  }
  dst[idx] = __float2bfloat16(v);
}

// ---------------------------------------------------------------------------
// Prep: folded MLP-in weights (f32), presummed LSTM biases, concat GAT biases.
// ---------------------------------------------------------------------------
__global__ void prep_w_k(
    const float* __restrict__ miw0, const float* __restrict__ mib0,
    const float* __restrict__ miw1, const float* __restrict__ mib1,
    const float* __restrict__ bih0, const float* __restrict__ bhh0,
    const float* __restrict__ bih1, const float* __restrict__ bhh1,
    const float* __restrict__ bl0, const float* __restrict__ br0,
    const float* __restrict__ bl1, const float* __restrict__ br1,
    float* __restrict__ Wp, float* __restrict__ bp,
    float* __restrict__ bsum, float* __restrict__ gblr)
{
  int t = threadIdx.x;
  for (int idx = t; idx < HID*INDIM; idx += 256){
    int j = idx >> 4, d = idx & 15;
    float s = 0.f;
    for (int k=0;k<HID;k++) s += miw1[j*HID+k] * miw0[k*INDIM+d];
    Wp[idx] = s;
  }
  for (int j = t; j < HID; j += 256){
    float s = mib1[j];
    for (int k=0;k<HID;k++) s += miw1[j*HID+k] * mib0[k];
    bp[j] = s;
  }
  for (int i = t; i < GDIM; i += 256){
    bsum[i]        = bih0[i] + bhh0[i];
    bsum[GDIM + i] = bih1[i] + bhh1[i];
  }
  for (int i = t; i < GDIM; i += 256){
    gblr[i]          = bl0[i];
    gblr[GDIM + i]   = br0[i];
    gblr[1024 + i]   = bl1[i];
    gblr[1536 + i]   = br1[i];
  }
}

// ---------------------------------------------------------------------------
// MLP-in: 64-row x-tile in LDS, W row in registers. Grid 3750.
// ---------------------------------------------------------------------------
__global__ __launch_bounds__(256) void mlp_in_k(
    const float* __restrict__ x, const float* __restrict__ Wp,
    const float* __restrict__ bp, bf16* __restrict__ X0)
{
  __shared__ __align__(16) float xs[64*16];
  const int tid = threadIdx.x;
  const int m0 = blockIdx.x*64;
  {
    int row = tid >> 2, q = tid & 3;
    int m = m0 + row;
    int t = m / NNODES, n = m - t*NNODES;
    float4 v = *(const float4*)(x + ((size_t)n*TLEN + t)*INDIM + q*4);
    *(float4*)(xs + row*16 + q*4) = v;
  }
  const int j = tid & 127;
  const int half = tid >> 7;
  const float* wr = Wp + j*INDIM;
  float4 w0 = *(const float4*)(wr);
  float4 w1 = *(const float4*)(wr + 4);
  float4 w2 = *(const float4*)(wr + 8);
  float4 w3 = *(const float4*)(wr + 12);
  float bj = bp[j];
  __syncthreads();
  #pragma unroll 4
  for (int mi=0; mi<32; mi++){
    int row = mi*2 + half;
    const float* xr = xs + row*16;
    float4 a0 = *(const float4*)(xr);
    float4 a1 = *(const float4*)(xr + 4);
    float4 a2 = *(const float4*)(xr + 8);
    float4 a3 = *(const float4*)(xr + 12);
    float s = bj
      + a0.x*w0.x + a0.y*w0.y + a0.z*w0.z + a0.w*w0.w
      + a1.x*w1.x + a1.y*w1.y + a1.z*w1.z + a1.w*w1.w
      + a2.x*w2.x + a2.y*w2.y + a2.z*w2.z + a2.w*w2.w
      + a3.x*w3.x + a3.y*w3.y + a3.z*w3.z + a3.w*w3.w;
    s = s > 0.f ? s : 0.f;
    X0[(size_t)(m0+row)*HID + j] = __float2bfloat16(s);
  }
}

// ---------------------------------------------------------------------------
// LSTM, one layer, 24 steps, register-resident weights + X prefetch +
// fast transcendentals. Block 512 thr = 8 waves; wave w owns hidden cols
// [16w,16w+16) of all 4 gates (128 VGPR of weights, loaded once).
// Block owns 48 rows; h in LDS; c in 12 regs/lane.
// WRITE_ALL=1: h[t] written in-place over Xin[t] (own rows only).
// ---------------------------------------------------------------------------
template<int WRITE_ALL>
__global__ __launch_bounds__(512, 2) void lstm_half(
    const bf16* __restrict__ Xin, const bf16* __restrict__ Wih,
    const bf16* __restrict__ Whh, const float* __restrict__ bias,
    bf16* __restrict__ out)
{
  __shared__ __align__(16) bf16 hs[48*136];
  const int tid = threadIdx.x;
  const int lane = tid & 63, w = tid >> 6;
  const int r16 = lane & 15, quad = lane >> 4;
  const int m0 = blockIdx.x*48;

  // weights -> registers (once)
  v8s wbi[4][4], wbh[4][4];
  #pragma unroll
  for (int g=0; g<4; g++)
    #pragma unroll
    for (int kc=0; kc<4; kc++){
      size_t o = (size_t)(g*HID + w*16 + r16)*HID + kc*32 + quad*8;
      wbi[g][kc] = *(const v8s*)(Wih + o);
      wbh[g][kc] = *(const v8s*)(Whh + o);
    }
  float bg[4];
  #pragma unroll
  for (int g=0; g<4; g++) bg[g] = bias[g*HID + w*16 + r16];

  // clamped A-row offsets
  size_t rowoff[3];
  #pragma unroll
  for (int mi=0; mi<3; mi++){
    int r = m0 + mi*16 + r16;
    rowoff[mi] = (size_t)(r < NNODES ? r : NNODES-1) * HID;
  }

  float c[12];
  #pragma unroll
  for (int i=0;i<12;i++) c[i] = 0.f;

  // zero h state
  for (int i = tid; i < 816; i += 512)
    *(uint4*)((char*)hs + i*16) = make_uint4(0,0,0,0);

  // preload X[0] fragments
  v8s ax[3][4];
  #pragma unroll
  for (int kc=0; kc<4; kc++)
    #pragma unroll
    for (int mi=0; mi<3; mi++)
      ax[mi][kc] = *(const v8s*)(Xin + rowoff[mi] + kc*32 + quad*8);

  __syncthreads();

  for (int t=0; t<TLEN; t++){
    v4f acc[3][4];
    #pragma unroll
    for (int mi=0;mi<3;mi++)
      #pragma unroll
      for (int g=0;g<4;g++) acc[mi][g] = (v4f)0.f;

    // ih from prefetched registers
    #pragma unroll
    for (int kc=0; kc<4; kc++)
      #pragma unroll
      for (int mi=0;mi<3;mi++)
        #pragma unroll
        for (int g=0;g<4;g++)
          acc[mi][g] = __builtin_amdgcn_mfma_f32_16x16x32_bf16(ax[mi][kc], wbi[g][kc], acc[mi][g], 0, 0, 0);

    // prefetch X[t+1] into the just-consumed registers (latency hidden by
    // hh phase + epilogue; compiler inserts the waitcnt before next use)
    if (t+1 < TLEN){
      const bf16* Xn = Xin + (size_t)(t+1)*NNODES*HID;
      #pragma unroll
      for (int kc=0; kc<4; kc++)
        #pragma unroll
        for (int mi=0; mi<3; mi++)
          ax[mi][kc] = *(const v8s*)(Xn + rowoff[mi] + kc*32 + quad*8);
    }

    // hh from LDS h[t-1]
    #pragma unroll
    for (int kc=0; kc<4; kc++){
      v8s av[3];
      #pragma unroll
      for (int mi=0;mi<3;mi++)
        av[mi] = *(const v8s*)(hs + (mi*16 + r16)*136 + kc*32 + quad*8);
      #pragma unroll
      for (int mi=0;mi<3;mi++)
        #pragma unroll
        for (int g=0;g<4;g++)
          acc[mi][g] = __builtin_amdgcn_mfma_f32_16x16x32_bf16(av[mi], wbh[g][kc], acc[mi][g], 0, 0, 0);
    }
    __syncthreads();   // all reads of hs complete

    #pragma unroll
    for (int mi=0;mi<3;mi++)
      #pragma unroll
      for (int r=0;r<4;r++){
        int lrow = mi*16 + quad*4 + r;
        float iv = acc[mi][0][r] + bg[0];
        float fv = acc[mi][1][r] + bg[1];
        float gv = acc[mi][2][r] + bg[2];
        float ov = acc[mi][3][r] + bg[3];
        float ig = fsig(iv), fg = fsig(fv);
        float gg = ftanh(gv), og = fsig(ov);
        int ci = mi*4 + r;
        float cn = fg*c[ci] + ig*gg;
        c[ci] = cn;
        hs[lrow*136 + w*16 + r16] = __float2bfloat16(og*ftanh(cn));
      }
    __syncthreads();   // h[t] visible

    if (WRITE_ALL){
      bf16* dst = (bf16*)(Xin + (size_t)t*NNODES*HID);  // own rows only
      for (int i = tid; i < 768; i += 512){
        int row = i >> 4, c8 = (i & 15) * 8;
        if (m0 + row < NNODES)
          *(uint4*)(dst + (size_t)(m0+row)*HID + c8) = *(const uint4*)(hs + row*136 + c8);
      }
    }
  }

  if (!WRITE_ALL){
    for (int i = tid; i < 768; i += 512){
      int row = i >> 4, c8 = (i & 15) * 8;
      if (m0 + row < NNODES)
        *(uint4*)(out + (size_t)(m0+row)*HID + c8) = *(const uint4*)(hs + row*136 + c8);
    }
  }
}

// ---------------------------------------------------------------------------
// Generic bf16 GEMM: C[M,N] = act(A[M,K] @ B[N,K]^T + bias_f32[N]), bf16 out.
// ---------------------------------------------------------------------------
template<int ACT>
__global__ __launch_bounds__(256) void gemm_bt(
    const bf16* __restrict__ A, const bf16* __restrict__ B,
    const float* __restrict__ bias, bf16* __restrict__ C,
    int M, int N, int K)
{
  __shared__ __align__(16) bf16 As[128*40];
  __shared__ __align__(16) bf16 Bs[128*40];
  const int tid = threadIdx.x;
  const int m0 = blockIdx.x*128, n0 = blockIdx.y*128;
  const int lane = tid & 63, wave = tid >> 6;
  const int r16 = lane & 15, quad = lane >> 4;

  v4f acc[2][8];
  #pragma unroll
  for (int a=0;a<2;a++)
    #pragma unroll
    for (int b=0;b<8;b++) acc[a][b] = (v4f)0.f;

  for (int k0=0; k0<K; k0+=32){
    #pragma unroll
    for (int i=0;i<2;i++){
      int li = tid + i*256;
      int row = li >> 2, q4 = li & 3;
      uint4 va = make_uint4(0,0,0,0);
      int gm = m0 + row;
      if (gm < M) va = *(const uint4*)(A + (size_t)gm*K + k0 + q4*8);
      *(uint4*)(As + row*40 + q4*8) = va;
      uint4 vb = make_uint4(0,0,0,0);
      int gn = n0 + row;
      if (gn < N) vb = *(const uint4*)(B + (size_t)gn*K + k0 + q4*8);
      *(uint4*)(Bs + row*40 + q4*8) = vb;
    }
    __syncthreads();
    v8s av[2], bv[8];
    #pragma unroll
    for (int mi=0;mi<2;mi++)
      av[mi] = *(const v8s*)(As + (wave*32 + mi*16 + r16)*40 + quad*8);
    #pragma unroll
    for (int ni=0;ni<8;ni++)
      bv[ni] = *(const v8s*)(Bs + (ni*16 + r16)*40 + quad*8);
    #pragma unroll
    for (int mi=0;mi<2;mi++)
      #pragma unroll
      for (int ni=0;ni<8;ni++)
        acc[mi][ni] = __builtin_amdgcn_mfma_f32_16x16x32_bf16(av[mi], bv[ni], acc[mi][ni], 0, 0, 0);
    __syncthreads();
  }

  #pragma unroll
  for (int mi=0;mi<2;mi++){
    #pragma unroll
    for (int r=0;r<4;r++){
      int row = m0 + wave*32 + mi*16 + quad*4 + r;
      if (row >= M) continue;
      #pragma unroll
      for (int ni=0;ni<8;ni++){
        int col = n0 + ni*16 + r16;
        float v = acc[mi][ni][r] + bias[col];
        if (ACT == 1) v = v > 0.f ? v : 0.f;
        C[(size_t)row*N + col] = __float2bfloat16(v);
      }
    }
  }
}

// ---------------------------------------------------------------------------
// CSR build (payload = resolved src id)
// ---------------------------------------------------------------------------
__global__ void deg_count_k(const int* __restrict__ dst, int* __restrict__ deg, int E){
  int e = blockIdx.x*256 + threadIdx.x;
  if (e < E){
    unsigned d = (unsigned)dst[e];
    if (d < (unsigned)NNODES) atomicAdd(&deg[d], 1);
  }
}

__global__ void scan_k(const int* __restrict__ deg, int* __restrict__ offs,
                       int* __restrict__ cursor, int n)
{
  __shared__ int part[256];
  __shared__ int base[256];
  int t = threadIdx.x;
  int lo = t*40, hi = lo+40;
  if (lo > n) lo = n;
  if (hi > n) hi = n;
  int s = 0;
  for (int i=lo;i<hi;i++) s += deg[i];
  part[t] = s;
  __syncthreads();
  if (t == 0){
    int run=0;
    for (int i=0;i<256;i++){ base[i]=run; run+=part[i]; }
    offs[n] = run;
  }
  __syncthreads();
  int run = base[t];
  for (int i=lo;i<hi;i++){ offs[i]=run; cursor[i]=run; run += deg[i]; }
}

__global__ void fill_k(const int* __restrict__ src, const int* __restrict__ dst,
                       int* __restrict__ cursor, int* __restrict__ srcs, int E){
  int e = blockIdx.x*256 + threadIdx.x;
  if (e < E){
    unsigned d = (unsigned)dst[e];
    if (d < (unsigned)NNODES){
      int p = atomicAdd(&cursor[d], 1);
      unsigned s = (unsigned)src[e];
      srcs[p] = (s < (unsigned)NNODES) ? (int)s : 0;
    }
  }
}

// ---------------------------------------------------------------------------
// GATv2 online-softmax fused score+aggregate. 1 wave/dst node.
// ---------------------------------------------------------------------------
__global__ __launch_bounds__(256) void gat_onl(
    const int* __restrict__ offs, const int* __restrict__ srcs,
    const bf16* __restrict__ xc, const float* __restrict__ att,
    const float* __restrict__ gbias, bf16* __restrict__ agg)
{
  int d = blockIdx.x*4 + (threadIdx.x >> 6);
  if (d >= NNODES) return;
  int lane = threadIdx.x & 63;
  float fr[8];
  unpack8(*(const uint4*)(xc + (size_t)d*1024 + 512 + lane*8), fr);
  float4 a0 = *(const float4*)(att + lane*8);
  float4 a1 = *(const float4*)(att + lane*8 + 4);
  float fa[8] = {a0.x,a0.y,a0.z,a0.w,a1.x,a1.y,a1.z,a1.w};
  int i0 = offs[d], i1 = offs[d+1];

  float m = -3.4e38f, den = 0.f;
  float acc[8] = {0,0,0,0,0,0,0,0};
  for (int i=i0; i<i1; i++){
    int s = srcs[i];
    float fl[8];
    unpack8(*(const uint4*)(xc + (size_t)s*1024 + lane*8), fl);
    float p = 0.f;
    #pragma unroll
    for (int q=0;q<8;q++){
      float v = fl[q] + fr[q];
      v = v > 0.f ? v : 0.2f*v;
      p += v*fa[q];
    }
    p += __shfl_xor(p, 1); p += __shfl_xor(p, 2);
    p += __shfl_xor(p, 4); p += __shfl_xor(p, 8);
    float mn = fmaxf(m, p);
    float corr = __expf(m - mn);
    float w = __expf(p - mn);
    den = den*corr + w;
    #pragma unroll
    for (int q=0;q<8;q++) acc[q] = acc[q]*corr + w*fl[q];
    m = mn;
  }
  float r = 1.f/(den + 1e-16f);
  float4 b0 = *(const float4*)(gbias + lane*8);
  float4 b1 = *(const float4*)(gbias + lane*8 + 4);
  float fb[8] = {b0.x,b0.y,b0.z,b0.w,b1.x,b1.y,b1.z,b1.w};
  #pragma unroll
  for (int q=0;q<8;q++)
    agg[(size_t)d*GDIM + lane*8 + q] = __float2bfloat16(acc[q]*r + fb[q]);
}

// ---------------------------------------------------------------------------
// Final linear (N=24): f32 weights, f32 out.
// ---------------------------------------------------------------------------
__global__ __launch_bounds__(256) void mlp_final_k(
    const bf16* __restrict__ a, const float* __restrict__ w,
    const float* __restrict__ b, float* __restrict__ out)
{
  int g = blockIdx.x*256 + threadIdx.x;
  if (g >= NNODES*24) return;
  int j = g % 24;
  int row = g / 24;
  const bf16* ar = a + (size_t)row*HID;
  const float* wr = w + (size_t)j*HID;
  float s = b[j];
  for (int k=0;k<HID;k+=8){
    float fa[8];
    unpack8(*(const uint4*)(ar+k), fa);
    float4 w0 = *(const float4*)(wr + k);
    float4 w1 = *(const float4*)(wr + k + 4);
    s += fa[0]*w0.x + fa[1]*w0.y + fa[2]*w0.z + fa[3]*w0.w
       + fa[4]*w1.x + fa[5]*w1.y + fa[6]*w1.z + fa[7]*w1.w;
  }
  out[g] = s;
}

// ---------------------------------------------------------------------------

extern "C" void kernel_launch(void* const* d_in, const int* in_sizes, int n_in,
                              void* d_out, int out_size, void* d_ws, size_t ws_size,
                              hipStream_t stream)
{
  const float* x   = (const float*)d_in[0];
  const int*   ei  = (const int*)d_in[1];
  const int E = in_sizes[1] / 2;
  const int* srcp = ei;
  const int* dstp = ei + E;

  const float* miw0 = (const float*)d_in[2];
  const float* mib0 = (const float*)d_in[3];
  const float* miw1 = (const float*)d_in[4];
  const float* mib1 = (const float*)d_in[5];
  const float* wih0 = (const float*)d_in[6];
  const float* whh0 = (const float*)d_in[7];
  const float* bih0 = (const float*)d_in[8];
  const float* bhh0 = (const float*)d_in[9];
  const float* wih1 = (const float*)d_in[10];
  const float* whh1 = (const float*)d_in[11];
  const float* bih1 = (const float*)d_in[12];
  const float* bhh1 = (const float*)d_in[13];
  const float* g_wl[2]   = {(const float*)d_in[14], (const float*)d_in[22]};
  const float* g_bl[2]   = {(const float*)d_in[15], (const float*)d_in[23]};
  const float* g_wr[2]   = {(const float*)d_in[16], (const float*)d_in[24]};
  const float* g_br[2]   = {(const float*)d_in[17], (const float*)d_in[25]};
  const float* g_att[2]  = {(const float*)d_in[18], (const float*)d_in[26]};
  const float* g_bias[2] = {(const float*)d_in[19], (const float*)d_in[27]};
  const float* g_pw[2]   = {(const float*)d_in[20], (const float*)d_in[28]};
  const float* g_pb[2]   = {(const float*)d_in[21], (const float*)d_in[29]};
  const float* mow0 = (const float*)d_in[30];
  const float* mob0 = (const float*)d_in[31];
  const float* mow1 = (const float*)d_in[32];
  const float* mob1 = (const float*)d_in[33];
  (void)n_in; (void)out_size; (void)ws_size;

  // ---- workspace layout ----
  char* base = (char*)d_ws;
  size_t off = 0;
  auto carve = [&](size_t n)->char*{
    char* p = base + off;
    off = (off + n + 255) & ~(size_t)255;
    return p;
  };
  char*  X0r = carve((size_t)TLEN*NNODES*HID*2);   // 61,440,000
  bf16*  zf  = (bf16*)carve((size_t)NNODES*HID*2);
  float* Wp  = (float*)carve(HID*INDIM*4);
  float* bp  = (float*)carve(HID*4);
  float* bsum= (float*)carve(2*GDIM*4);
  float* gblr= (float*)carve(2*1024*4);
  bf16*  wbf = (bf16*)carve((size_t)671744*2);
  int*   offsb = (int*)carve((size_t)(NNODES+1)*4);
  int*   curs  = (int*)carve((size_t)NNODES*4);
  int*   srcs  = (int*)carve((size_t)E*4);
  int*   deg   = (int*)carve((size_t)NNODES*4);
  bf16*  agg   = (bf16*)carve((size_t)NNODES*GDIM*2);

  // wbf sub-pointers (conv_w_k chunk order)
  const bf16* wih0b = wbf + 0;
  const bf16* whh0b = wbf + 65536;
  const bf16* wih1b = wbf + 131072;
  const bf16* whh1b = wbf + 196608;
  const bf16* wlr0b = wbf + 262144;   // wl0|wr0 contiguous [1024,128]
  const bf16* pw0b  = wbf + 393216;
  const bf16* wlr1b = wbf + 458752;   // wl1|wr1 contiguous
  const bf16* pw1b  = wbf + 589824;
  const bf16* mow0b = wbf + 655360;
  const bf16* wlrb[2] = {wlr0b, wlr1b};
  const bf16* pwb[2]  = {pw0b, pw1b};

  // X0 region aliases (holds X0, then h1 in-place, dead after LSTM)
  bf16* X0 = (bf16*)X0r;
  bf16* xc = (bf16*)X0r;                      // [10000,1024] = xl|xr
  bf16* z2 = (bf16*)(X0r + 20480000);
  bf16* z3 = (bf16*)(X0r + 23040000);
  bf16* o0 = (bf16*)(X0r + 25600000);

  // ---- prep ----
  conv_w_k<<<2624, 256, 0, stream>>>(wih0, whh0, wih1, whh1,
                                     g_wl[0], g_wr[0], g_pw[0],
                                     g_wl[1], g_wr[1], g_pw[1], mow0, wbf);
  prep_w_k<<<1, 256, 0, stream>>>(miw0, mib0, miw1, mib1,
                                  bih0, bhh0, bih1, bhh1,
                                  g_bl[0], g_br[0], g_bl[1], g_br[1],
                                  Wp, bp, bsum, gblr);
  hipMemsetAsync(deg, 0, (size_t)NNODES*4, stream);

  // ---- MLP in ----
  mlp_in_k<<<(TLEN*NNODES)/64, 256, 0, stream>>>(x, Wp, bp, X0);

  // ---- CSR build ----
  deg_count_k<<<(E+255)/256, 256, 0, stream>>>(dstp, deg, E);
  scan_k<<<1, 256, 0, stream>>>(deg, offsb, curs, NNODES);
  fill_k<<<(E+255)/256, 256, 0, stream>>>(srcp, dstp, curs, srcs, E);

  // ---- LSTM: layer 1 (h1 in-place over X0), then layer 2 ----
  const int NBL = (NNODES + 47) / 48;   // 209 blocks
  lstm_half<1><<<NBL, 512, 0, stream>>>(X0, wih0b, whh0b, bsum, nullptr);
  lstm_half<0><<<NBL, 512, 0, stream>>>(X0, wih1b, whh1b, bsum + GDIM, zf);

  // ---- GAT layers ----
  const bf16* zin = zf;
  bf16* zouts[2] = {z2, z3};
  for (int l=0; l<2; l++){
    gemm_bt<0><<<dim3(79,8), 256, 0, stream>>>(zin, wlrb[l], gblr + l*1024, xc, NNODES, 1024, HID);
    gat_onl<<<(NNODES+3)/4, 256, 0, stream>>>(offsb, srcs, xc, g_att[l], g_bias[l], agg);
    gemm_bt<1><<<dim3(79,1), 256, 0, stream>>>(agg, pwb[l], g_pb[l], zouts[l], NNODES, HID, GDIM);
    zin = zouts[l];
  }

  // ---- MLP out ----
  gemm_bt<1><<<dim3(79,1), 256, 0, stream>>>(z3, mow0b, mob0, o0, NNODES, HID, HID);
  mlp_final_k<<<(NNODES*24+255)/256, 256, 0, stream>>>(o0, mow1, mob1, (float*)d_out);
}

// Round 10
// 651.881 us; speedup vs baseline: 6.6832x; 1.0961x over previous
//
#include <hip/hip_runtime.h>
#include <hip/hip_bf16.h>

#define NNODES 10000
#define TLEN 24
#define INDIM 16
#define HID 128
#define GDIM 512   // 4*HID (LSTM gates) == HEADS*HID (GAT)

typedef __hip_bfloat16 bf16;
typedef short v8s __attribute__((ext_vector_type(8)));
typedef float v4f __attribute__((ext_vector_type(4)));

__device__ inline float u2f(unsigned u){ return __uint_as_float(u); }

__device__ inline void unpack8(uint4 v, float* f){
  f[0]=u2f(v.x<<16); f[1]=u2f(v.x&0xFFFF0000u);
  f[2]=u2f(v.y<<16); f[3]=u2f(v.y&0xFFFF0000u);
  f[4]=u2f(v.z<<16); f[5]=u2f(v.z&0xFFFF0000u);
  f[6]=u2f(v.w<<16); f[7]=u2f(v.w&0xFFFF0000u);
}

__device__ inline float sigm(float x){ return 1.f/(1.f+__expf(-x)); }

// fast device transcendentals (v_exp_f32 + v_rcp_f32; inf-safe)
__device__ inline float fsig(float x){
  return __builtin_amdgcn_rcpf(1.f + __expf(-x));
}
__device__ inline float ftanh(float x){
  float t = __expf(-2.f*fabsf(x));           // in (0,1], no overflow
  float r = (1.f - t) * __builtin_amdgcn_rcpf(1.f + t);
  return copysignf(r, x);
}

// ---------------------------------------------------------------------------
// Convert 11 f32 weight matrices (MFMA B-operands) to bf16.
// Order: wih0,whh0,wih1,whh1, wl0,wr0,pw0, wl1,wr1,pw1 (65536 ea), mow0 (16384).
// ---------------------------------------------------------------------------
__global__ __launch_bounds__(256) void conv_w_k(
    const float* s0, const float* s1, const float* s2, const float* s3,
    const float* s4, const float* s5, const float* s6, const float* s7,
    const float* s8, const float* s9, const float* s10, bf16* __restrict__ dst)
{
  int idx = blockIdx.x*256 + threadIdx.x;
  if (idx >= 671744) return;
  int c = idx >> 16;
  float v;
  if (c < 10){
    const float* srcs[10] = {s0,s1,s2,s3,s4,s5,s6,s7,s8,s9};
    v = srcs[c][idx & 0xFFFF];
  } else {
    v = s10[idx - 655360];
  }
  dst[idx] = __float2bfloat16(v);
}

// ---------------------------------------------------------------------------
// Prep: folded MLP-in weights (f32), presummed LSTM biases, concat GAT biases.
// ---------------------------------------------------------------------------
__global__ void prep_w_k(
    const float* __restrict__ miw0, const float* __restrict__ mib0,
    const float* __restrict__ miw1, const float* __restrict__ mib1,
    const float* __restrict__ bih0, const float* __restrict__ bhh0,
    const float* __restrict__ bih1, const float* __restrict__ bhh1,
    const float* __restrict__ bl0, const float* __restrict__ br0,
    const float* __restrict__ bl1, const float* __restrict__ br1,
    float* __restrict__ Wp, float* __restrict__ bp,
    float* __restrict__ bsum, float* __restrict__ gblr)
{
  int t = threadIdx.x;
  for (int idx = t; idx < HID*INDIM; idx += 256){
    int j = idx >> 4, d = idx & 15;
    float s = 0.f;
    for (int k=0;k<HID;k++) s += miw1[j*HID+k] * miw0[k*INDIM+d];
    Wp[idx] = s;
  }
  for (int j = t; j < HID; j += 256){
    float s = mib1[j];
    for (int k=0;k<HID;k++) s += miw1[j*HID+k] * mib0[k];
    bp[j] = s;
  }
  for (int i = t; i < GDIM; i += 256){
    bsum[i]        = bih0[i] + bhh0[i];
    bsum[GDIM + i] = bih1[i] + bhh1[i];
  }
  for (int i = t; i < GDIM; i += 256){
    gblr[i]          = bl0[i];
    gblr[GDIM + i]   = br0[i];
    gblr[1024 + i]   = bl1[i];
    gblr[1536 + i]   = br1[i];
  }
}

// ---------------------------------------------------------------------------
// MLP-in: 64-row x-tile in LDS, W row in registers. Grid 3750.
// ---------------------------------------------------------------------------
__global__ __launch_bounds__(256) void mlp_in_k(
    const float* __restrict__ x, const float* __restrict__ Wp,
    const float* __restrict__ bp, bf16* __restrict__ X0)
{
  __shared__ __align__(16) float xs[64*16];
  const int tid = threadIdx.x;
  const int m0 = blockIdx.x*64;
  {
    int row = tid >> 2, q = tid & 3;
    int m = m0 + row;
    int t = m / NNODES, n = m - t*NNODES;
    float4 v = *(const float4*)(x + ((size_t)n*TLEN + t)*INDIM + q*4);
    *(float4*)(xs + row*16 + q*4) = v;
  }
  const int j = tid & 127;
  const int half = tid >> 7;
  const float* wr = Wp + j*INDIM;
  float4 w0 = *(const float4*)(wr);
  float4 w1 = *(const float4*)(wr + 4);
  float4 w2 = *(const float4*)(wr + 8);
  float4 w3 = *(const float4*)(wr + 12);
  float bj = bp[j];
  __syncthreads();
  #pragma unroll 4
  for (int mi=0; mi<32; mi++){
    int row = mi*2 + half;
    const float* xr = xs + row*16;
    float4 a0 = *(const float4*)(xr);
    float4 a1 = *(const float4*)(xr + 4);
    float4 a2 = *(const float4*)(xr + 8);
    float4 a3 = *(const float4*)(xr + 12);
    float s = bj
      + a0.x*w0.x + a0.y*w0.y + a0.z*w0.z + a0.w*w0.w
      + a1.x*w1.x + a1.y*w1.y + a1.z*w1.z + a1.w*w1.w
      + a2.x*w2.x + a2.y*w2.y + a2.z*w2.z + a2.w*w2.w
      + a3.x*w3.x + a3.y*w3.y + a3.z*w3.z + a3.w*w3.w;
    s = s > 0.f ? s : 0.f;
    X0[(size_t)(m0+row)*HID + j] = __float2bfloat16(s);
  }
}

// ---------------------------------------------------------------------------
// LSTM, one layer, 24 steps. Register-resident weights, X prefetch, fast
// transcendentals, DOUBLE-BUFFERED LDS h (one barrier/step), and the t-loop
// kept ROLLED (#pragma unroll 1) so the ~700-instr body stays I-cache
// resident (full unroll = ~120KB of code streamed from L2 every step).
// ---------------------------------------------------------------------------
template<int WRITE_ALL>
__global__ __launch_bounds__(512, 2) void lstm_half(
    const bf16* __restrict__ Xin, const bf16* __restrict__ Wih,
    const bf16* __restrict__ Whh, const float* __restrict__ bias,
    bf16* __restrict__ out)
{
  __shared__ __align__(16) bf16 hsA[48*136];
  __shared__ __align__(16) bf16 hsB[48*136];
  const int tid = threadIdx.x;
  const int lane = tid & 63, w = tid >> 6;
  const int r16 = lane & 15, quad = lane >> 4;
  const int m0 = blockIdx.x*48;

  // weights -> registers (once)
  v8s wbi[4][4], wbh[4][4];
  #pragma unroll
  for (int g=0; g<4; g++)
    #pragma unroll
    for (int kc=0; kc<4; kc++){
      size_t o = (size_t)(g*HID + w*16 + r16)*HID + kc*32 + quad*8;
      wbi[g][kc] = *(const v8s*)(Wih + o);
      wbh[g][kc] = *(const v8s*)(Whh + o);
    }
  float bg[4];
  #pragma unroll
  for (int g=0; g<4; g++) bg[g] = bias[g*HID + w*16 + r16];

  // clamped A-row offsets
  size_t rowoff[3];
  #pragma unroll
  for (int mi=0; mi<3; mi++){
    int r = m0 + mi*16 + r16;
    rowoff[mi] = (size_t)(r < NNODES ? r : NNODES-1) * HID;
  }

  float c[12];
  #pragma unroll
  for (int i=0;i<12;i++) c[i] = 0.f;

  // zero both h buffers (t=0 reads hsB)
  for (int i = tid; i < 816; i += 512){
    *(uint4*)((char*)hsA + i*16) = make_uint4(0,0,0,0);
    *(uint4*)((char*)hsB + i*16) = make_uint4(0,0,0,0);
  }

  // preload X[0] fragments
  v8s ax[3][4];
  #pragma unroll
  for (int kc=0; kc<4; kc++)
    #pragma unroll
    for (int mi=0; mi<3; mi++)
      ax[mi][kc] = *(const v8s*)(Xin + rowoff[mi] + kc*32 + quad*8);

  __syncthreads();

  #pragma unroll 1
  for (int t=0; t<TLEN; t++){
    // h[t] -> buf[t&1]; h[t-1] in buf[(t-1)&1]; t=0 reads zeroed hsB
    bf16* hrd = (t & 1) ? hsA : hsB;
    bf16* hwr = (t & 1) ? hsB : hsA;

    v4f acc[3][4];
    #pragma unroll
    for (int mi=0;mi<3;mi++)
      #pragma unroll
      for (int g=0;g<4;g++) acc[mi][g] = (v4f)0.f;

    // ih from prefetched registers
    #pragma unroll
    for (int kc=0; kc<4; kc++)
      #pragma unroll
      for (int mi=0;mi<3;mi++)
        #pragma unroll
        for (int g=0;g<4;g++)
          acc[mi][g] = __builtin_amdgcn_mfma_f32_16x16x32_bf16(ax[mi][kc], wbi[g][kc], acc[mi][g], 0, 0, 0);

    // prefetch X[t+1] (clamped; latency hidden by hh phase + epilogue)
    {
      int tn = t+1 < TLEN ? t+1 : TLEN-1;
      const bf16* Xn = Xin + (size_t)tn*NNODES*HID;
      #pragma unroll
      for (int kc=0; kc<4; kc++)
        #pragma unroll
        for (int mi=0; mi<3; mi++)
          ax[mi][kc] = *(const v8s*)(Xn + rowoff[mi] + kc*32 + quad*8);
    }

    // hh from LDS h[t-1]
    #pragma unroll
    for (int kc=0; kc<4; kc++){
      v8s av[3];
      #pragma unroll
      for (int mi=0;mi<3;mi++)
        av[mi] = *(const v8s*)(hrd + (mi*16 + r16)*136 + kc*32 + quad*8);
      #pragma unroll
      for (int mi=0;mi<3;mi++)
        #pragma unroll
        for (int g=0;g<4;g++)
          acc[mi][g] = __builtin_amdgcn_mfma_f32_16x16x32_bf16(av[mi], wbh[g][kc], acc[mi][g], 0, 0, 0);
    }

    // epilogue writes h[t] into hwr (different buffer than hrd -> no WAR)
    #pragma unroll
    for (int mi=0;mi<3;mi++)
      #pragma unroll
      for (int r=0;r<4;r++){
        int lrow = mi*16 + quad*4 + r;
        float iv = acc[mi][0][r] + bg[0];
        float fv = acc[mi][1][r] + bg[1];
        float gv = acc[mi][2][r] + bg[2];
        float ov = acc[mi][3][r] + bg[3];
        float ig = fsig(iv), fg = fsig(fv);
        float gg = ftanh(gv), og = fsig(ov);
        int ci = mi*4 + r;
        float cn = fg*c[ci] + ig*gg;
        c[ci] = cn;
        hwr[lrow*136 + w*16 + r16] = __float2bfloat16(og*ftanh(cn));
      }
    __syncthreads();   // h[t] visible (single barrier per step)

    if (WRITE_ALL){
      bf16* dst = (bf16*)(Xin + (size_t)t*NNODES*HID);  // own rows only
      for (int i = tid; i < 768; i += 512){
        int row = i >> 4, c8 = (i & 15) * 8;
        if (m0 + row < NNODES)
          *(uint4*)(dst + (size_t)(m0+row)*HID + c8) = *(const uint4*)(hwr + row*136 + c8);
      }
    }
  }

  if (!WRITE_ALL){
    const bf16* hfin = ((TLEN-1) & 1) ? hsB : hsA;
    for (int i = tid; i < 768; i += 512){
      int row = i >> 4, c8 = (i & 15) * 8;
      if (m0 + row < NNODES)
        *(uint4*)(out + (size_t)(m0+row)*HID + c8) = *(const uint4*)(hfin + row*136 + c8);
    }
  }
}

// ---------------------------------------------------------------------------
// Generic bf16 GEMM: C[M,N] = act(A[M,K] @ B[N,K]^T + bias_f32[N]), bf16 out.
// ---------------------------------------------------------------------------
template<int ACT>
__global__ __launch_bounds__(256) void gemm_bt(
    const bf16* __restrict__ A, const bf16* __restrict__ B,
    const float* __restrict__ bias, bf16* __restrict__ C,
    int M, int N, int K)
{
  __shared__ __align__(16) bf16 As[128*40];
  __shared__ __align__(16) bf16 Bs[128*40];
  const int tid = threadIdx.x;
  const int m0 = blockIdx.x*128, n0 = blockIdx.y*128;
  const int lane = tid & 63, wave = tid >> 6;
  const int r16 = lane & 15, quad = lane >> 4;

  v4f acc[2][8];
  #pragma unroll
  for (int a=0;a<2;a++)
    #pragma unroll
    for (int b=0;b<8;b++) acc[a][b] = (v4f)0.f;

  for (int k0=0; k0<K; k0+=32){
    #pragma unroll
    for (int i=0;i<2;i++){
      int li = tid + i*256;
      int row = li >> 2, q4 = li & 3;
      uint4 va = make_uint4(0,0,0,0);
      int gm = m0 + row;
      if (gm < M) va = *(const uint4*)(A + (size_t)gm*K + k0 + q4*8);
      *(uint4*)(As + row*40 + q4*8) = va;
      uint4 vb = make_uint4(0,0,0,0);
      int gn = n0 + row;
      if (gn < N) vb = *(const uint4*)(B + (size_t)gn*K + k0 + q4*8);
      *(uint4*)(Bs + row*40 + q4*8) = vb;
    }
    __syncthreads();
    v8s av[2], bv[8];
    #pragma unroll
    for (int mi=0;mi<2;mi++)
      av[mi] = *(const v8s*)(As + (wave*32 + mi*16 + r16)*40 + quad*8);
    #pragma unroll
    for (int ni=0;ni<8;ni++)
      bv[ni] = *(const v8s*)(Bs + (ni*16 + r16)*40 + quad*8);
    #pragma unroll
    for (int mi=0;mi<2;mi++)
      #pragma unroll
      for (int ni=0;ni<8;ni++)
        acc[mi][ni] = __builtin_amdgcn_mfma_f32_16x16x32_bf16(av[mi], bv[ni], acc[mi][ni], 0, 0, 0);
    __syncthreads();
  }

  #pragma unroll
  for (int mi=0;mi<2;mi++){
    #pragma unroll
    for (int r=0;r<4;r++){
      int row = m0 + wave*32 + mi*16 + quad*4 + r;
      if (row >= M) continue;
      #pragma unroll
      for (int ni=0;ni<8;ni++){
        int col = n0 + ni*16 + r16;
        float v = acc[mi][ni][r] + bias[col];
        if (ACT == 1) v = v > 0.f ? v : 0.f;
        C[(size_t)row*N + col] = __float2bfloat16(v);
      }
    }
  }
}

// ---------------------------------------------------------------------------
// CSR build (payload = resolved src id)
// ---------------------------------------------------------------------------
__global__ void deg_count_k(const int* __restrict__ dst, int* __restrict__ deg, int E){
  int e = blockIdx.x*256 + threadIdx.x;
  if (e < E){
    unsigned d = (unsigned)dst[e];
    if (d < (unsigned)NNODES) atomicAdd(&deg[d], 1);
  }
}

__global__ void scan_k(const int* __restrict__ deg, int* __restrict__ offs,
                       int* __restrict__ cursor, int n)
{
  __shared__ int part[256];
  __shared__ int base[256];
  int t = threadIdx.x;
  int lo = t*40, hi = lo+40;
  if (lo > n) lo = n;
  if (hi > n) hi = n;
  int s = 0;
  for (int i=lo;i<hi;i++) s += deg[i];
  part[t] = s;
  __syncthreads();
  if (t == 0){
    int run=0;
    for (int i=0;i<256;i++){ base[i]=run; run+=part[i]; }
    offs[n] = run;
  }
  __syncthreads();
  int run = base[t];
  for (int i=lo;i<hi;i++){ offs[i]=run; cursor[i]=run; run += deg[i]; }
}

__global__ void fill_k(const int* __restrict__ src, const int* __restrict__ dst,
                       int* __restrict__ cursor, int* __restrict__ srcs, int E){
  int e = blockIdx.x*256 + threadIdx.x;
  if (e < E){
    unsigned d = (unsigned)dst[e];
    if (d < (unsigned)NNODES){
      int p = atomicAdd(&cursor[d], 1);
      unsigned s = (unsigned)src[e];
      srcs[p] = (s < (unsigned)NNODES) ? (int)s : 0;
    }
  }
}

// ---------------------------------------------------------------------------
// GATv2 online-softmax fused score+aggregate. 1 wave/dst node.
// ---------------------------------------------------------------------------
__global__ __launch_bounds__(256) void gat_onl(
    const int* __restrict__ offs, const int* __restrict__ srcs,
    const bf16* __restrict__ xc, const float* __restrict__ att,
    const float* __restrict__ gbias, bf16* __restrict__ agg)
{
  int d = blockIdx.x*4 + (threadIdx.x >> 6);
  if (d >= NNODES) return;
  int lane = threadIdx.x & 63;
  float fr[8];
  unpack8(*(const uint4*)(xc + (size_t)d*1024 + 512 + lane*8), fr);
  float4 a0 = *(const float4*)(att + lane*8);
  float4 a1 = *(const float4*)(att + lane*8 + 4);
  float fa[8] = {a0.x,a0.y,a0.z,a0.w,a1.x,a1.y,a1.z,a1.w};
  int i0 = offs[d], i1 = offs[d+1];

  float m = -3.4e38f, den = 0.f;
  float acc[8] = {0,0,0,0,0,0,0,0};
  for (int i=i0; i<i1; i++){
    int s = srcs[i];
    float fl[8];
    unpack8(*(const uint4*)(xc + (size_t)s*1024 + lane*8), fl);
    float p = 0.f;
    #pragma unroll
    for (int q=0;q<8;q++){
      float v = fl[q] + fr[q];
      v = v > 0.f ? v : 0.2f*v;
      p += v*fa[q];
    }
    p += __shfl_xor(p, 1); p += __shfl_xor(p, 2);
    p += __shfl_xor(p, 4); p += __shfl_xor(p, 8);
    float mn = fmaxf(m, p);
    float corr = __expf(m - mn);
    float w = __expf(p - mn);
    den = den*corr + w;
    #pragma unroll
    for (int q=0;q<8;q++) acc[q] = acc[q]*corr + w*fl[q];
    m = mn;
  }
  float r = 1.f/(den + 1e-16f);
  float4 b0 = *(const float4*)(gbias + lane*8);
  float4 b1 = *(const float4*)(gbias + lane*8 + 4);
  float fb[8] = {b0.x,b0.y,b0.z,b0.w,b1.x,b1.y,b1.z,b1.w};
  #pragma unroll
  for (int q=0;q<8;q++)
    agg[(size_t)d*GDIM + lane*8 + q] = __float2bfloat16(acc[q]*r + fb[q]);
}

// ---------------------------------------------------------------------------
// Final linear (N=24): f32 weights, f32 out.
// ---------------------------------------------------------------------------
__global__ __launch_bounds__(256) void mlp_final_k(
    const bf16* __restrict__ a, const float* __restrict__ w,
    const float* __restrict__ b, float* __restrict__ out)
{
  int g = blockIdx.x*256 + threadIdx.x;
  if (g >= NNODES*24) return;
  int j = g % 24;
  int row = g / 24;
  const bf16* ar = a + (size_t)row*HID;
  const float* wr = w + (size_t)j*HID;
  float s = b[j];
  for (int k=0;k<HID;k+=8){
    float fa[8];
    unpack8(*(const uint4*)(ar+k), fa);
    float4 w0 = *(const float4*)(wr + k);
    float4 w1 = *(const float4*)(wr + k + 4);
    s += fa[0]*w0.x + fa[1]*w0.y + fa[2]*w0.z + fa[3]*w0.w
       + fa[4]*w1.x + fa[5]*w1.y + fa[6]*w1.z + fa[7]*w1.w;
  }
  out[g] = s;
}

// ---------------------------------------------------------------------------

extern "C" void kernel_launch(void* const* d_in, const int* in_sizes, int n_in,
                              void* d_out, int out_size, void* d_ws, size_t ws_size,
                              hipStream_t stream)
{
  const float* x   = (const float*)d_in[0];
  const int*   ei  = (const int*)d_in[1];
  const int E = in_sizes[1] / 2;
  const int* srcp = ei;
  const int* dstp = ei + E;

  const float* miw0 = (const float*)d_in[2];
  const float* mib0 = (const float*)d_in[3];
  const float* miw1 = (const float*)d_in[4];
  const float* mib1 = (const float*)d_in[5];
  const float* wih0 = (const float*)d_in[6];
  const float* whh0 = (const float*)d_in[7];
  const float* bih0 = (const float*)d_in[8];
  const float* bhh0 = (const float*)d_in[9];
  const float* wih1 = (const float*)d_in[10];
  const float* whh1 = (const float*)d_in[11];
  const float* bih1 = (const float*)d_in[12];
  const float* bhh1 = (const float*)d_in[13];
  const float* g_wl[2]   = {(const float*)d_in[14], (const float*)d_in[22]};
  const float* g_bl[2]   = {(const float*)d_in[15], (const float*)d_in[23]};
  const float* g_wr[2]   = {(const float*)d_in[16], (const float*)d_in[24]};
  const float* g_br[2]   = {(const float*)d_in[17], (const float*)d_in[25]};
  const float* g_att[2]  = {(const float*)d_in[18], (const float*)d_in[26]};
  const float* g_bias[2] = {(const float*)d_in[19], (const float*)d_in[27]};
  const float* g_pw[2]   = {(const float*)d_in[20], (const float*)d_in[28]};
  const float* g_pb[2]   = {(const float*)d_in[21], (const float*)d_in[29]};
  const float* mow0 = (const float*)d_in[30];
  const float* mob0 = (const float*)d_in[31];
  const float* mow1 = (const float*)d_in[32];
  const float* mob1 = (const float*)d_in[33];
  (void)n_in; (void)out_size; (void)ws_size;

  // ---- workspace layout ----
  char* base = (char*)d_ws;
  size_t off = 0;
  auto carve = [&](size_t n)->char*{
    char* p = base + off;
    off = (off + n + 255) & ~(size_t)255;
    return p;
  };
  char*  X0r = carve((size_t)TLEN*NNODES*HID*2);   // 61,440,000
  bf16*  zf  = (bf16*)carve((size_t)NNODES*HID*2);
  float* Wp  = (float*)carve(HID*INDIM*4);
  float* bp  = (float*)carve(HID*4);
  float* bsum= (float*)carve(2*GDIM*4);
  float* gblr= (float*)carve(2*1024*4);
  bf16*  wbf = (bf16*)carve((size_t)671744*2);
  int*   offsb = (int*)carve((size_t)(NNODES+1)*4);
  int*   curs  = (int*)carve((size_t)NNODES*4);
  int*   srcs  = (int*)carve((size_t)E*4);
  int*   deg   = (int*)carve((size_t)NNODES*4);
  bf16*  agg   = (bf16*)carve((size_t)NNODES*GDIM*2);

  // wbf sub-pointers (conv_w_k chunk order)
  const bf16* wih0b = wbf + 0;
  const bf16* whh0b = wbf + 65536;
  const bf16* wih1b = wbf + 131072;
  const bf16* whh1b = wbf + 196608;
  const bf16* wlr0b = wbf + 262144;   // wl0|wr0 contiguous [1024,128]
  const bf16* pw0b  = wbf + 393216;
  const bf16* wlr1b = wbf + 458752;   // wl1|wr1 contiguous
  const bf16* pw1b  = wbf + 589824;
  const bf16* mow0b = wbf + 655360;
  const bf16* wlrb[2] = {wlr0b, wlr1b};
  const bf16* pwb[2]  = {pw0b, pw1b};

  // X0 region aliases (holds X0, then h1 in-place, dead after LSTM)
  bf16* X0 = (bf16*)X0r;
  bf16* xc = (bf16*)X0r;                      // [10000,1024] = xl|xr
  bf16* z2 = (bf16*)(X0r + 20480000);
  bf16* z3 = (bf16*)(X0r + 23040000);
  bf16* o0 = (bf16*)(X0r + 25600000);

  // ---- prep ----
  conv_w_k<<<2624, 256, 0, stream>>>(wih0, whh0, wih1, whh1,
                                     g_wl[0], g_wr[0], g_pw[0],
                                     g_wl[1], g_wr[1], g_pw[1], mow0, wbf);
  prep_w_k<<<1, 256, 0, stream>>>(miw0, mib0, miw1, mib1,
                                  bih0, bhh0, bih1, bhh1,
                                  g_bl[0], g_br[0], g_bl[1], g_br[1],
                                  Wp, bp, bsum, gblr);
  hipMemsetAsync(deg, 0, (size_t)NNODES*4, stream);

  // ---- MLP in ----
  mlp_in_k<<<(TLEN*NNODES)/64, 256, 0, stream>>>(x, Wp, bp, X0);

  // ---- CSR build ----
  deg_count_k<<<(E+255)/256, 256, 0, stream>>>(dstp, deg, E);
  scan_k<<<1, 256, 0, stream>>>(deg, offsb, curs, NNODES);
  fill_k<<<(E+255)/256, 256, 0, stream>>>(srcp, dstp, curs, srcs, E);

  // ---- LSTM: layer 1 (h1 in-place over X0), then layer 2 ----
  const int NBL = (NNODES + 47) / 48;   // 209 blocks
  lstm_half<1><<<NBL, 512, 0, stream>>>(X0, wih0b, whh0b, bsum, nullptr);
  lstm_half<0><<<NBL, 512, 0, stream>>>(X0, wih1b, whh1b, bsum + GDIM, zf);

  // ---- GAT layers ----
  const bf16* zin = zf;
  bf16* zouts[2] = {z2, z3};
  for (int l=0; l<2; l++){
    gemm_bt<0><<<dim3(79,8), 256, 0, stream>>>(zin, wlrb[l], gblr + l*1024, xc, NNODES, 1024, HID);
    gat_onl<<<(NNODES+3)/4, 256, 0, stream>>>(offsb, srcs, xc, g_att[l], g_bias[l], agg);
    gemm_bt<1><<<dim3(79,1), 256, 0, stream>>>(agg, pwb[l], g_pb[l], zouts[l], NNODES, HID, GDIM);
    zin = zouts[l];
  }

  // ---- MLP out ----
  gemm_bt<1><<<dim3(79,1), 256, 0, stream>>>(z3, mow0b, mob0, o0, NNODES, HID, HID);
  mlp_final_k<<<(NNODES*24+255)/256, 256, 0, stream>>>(o0, mow1, mob1, (float*)d_out);
}